// Round 9
// baseline (1038.775 us; speedup 1.0000x reference)
//
#include <hip/hip_runtime.h>
#include <hip/hip_bf16.h>

#define NBATCH 256
#define TSE 168
#define TSD 24
#define NTOK (NBATCH*TSE)   // 43008
#define NDTOK (NBATCH*TSD)  // 6144

// PA-GRN transposed fp32 weights (floats, in wtp region)
#define OFF_PA_FC1T    0
#define OFF_PA_FC2T    16384
#define OFF_PA_GATET   32768

// packed bf16 MFMA-B-fragment offsets (ushort units, region base pk)
#define PK_VSN   0         // 9 x [K=128, NC=256]  = 294912
#define PK_GC1   294912    // [K=1152, NC=256]     = 294912
#define PK_GC2   589824    // [K=128, NC=256]      = 32768
#define PK_ENC0  622592    // [128,512]            = 65536
#define PK_DEC0  688128    // [128,512]            = 65536
#define PK_AIN   753664    // [128,384]            = 49152
#define PK_AOUT  802816    // [128,128]            = 16384

typedef __attribute__((ext_vector_type(8))) short short8;
typedef __attribute__((ext_vector_type(4))) float f32x4;
typedef __attribute__((ext_vector_type(2))) __fp16 fp16x2;

__device__ __forceinline__ float sigm(float x){ return 1.f/(1.f + __expf(-x)); }
__device__ __forceinline__ float tanhx(float x){
  float cx = fminf(fmaxf(x, -15.f), 15.f);
  float e = __expf(2.f*cx);
  return (e-1.f)/(e+1.f);
}
__device__ __forceinline__ float eluf(float x){ return x > 0.f ? x : (__expf(x)-1.f); }
__device__ __forceinline__ unsigned short f2bu(float v){
  unsigned int u = __float_as_uint(v);
  u = (u + 0x7fffu + ((u>>16)&1u)) >> 16;
  return (unsigned short)u;
}
__device__ __forceinline__ unsigned int pkh(float a, float b){
  union { fp16x2 h; unsigned int u; } v;
  v.h = __builtin_amdgcn_cvt_pkrtz(a, b);
  return v.u;
}
__device__ __forceinline__ unsigned short f2h(float x){
  union { _Float16 h; unsigned short u; } v;
  v.h = (_Float16)x; return v.u;
}
__device__ __forceinline__ float h2f(unsigned short u){
  union { unsigned short u; _Float16 h; } v;
  v.u = u; return (float)v.h;
}
__device__ __forceinline__ float fd2(unsigned int a, unsigned int b, float c){
  union { unsigned int u; fp16x2 h; } ua, ub;
  ua.u = a; ub.u = b;
  return __builtin_amdgcn_fdot2(ua.h, ub.h, c, false);
}

// ---------------- transpose 3 PA 128x128 fp32 weights ----------------------
__global__ __launch_bounds__(256) void k_transpose3(float* __restrict__ wtp,
    const float* s0, const float* s1, const float* s2)
{
  int idx = blockIdx.x*256 + threadIdx.x;
  if (idx >= 49152) return;
  int s = idx >> 14, li = idx & 16383;
  int r = li >> 7, c = li & 127;
  const float* src = (s == 0) ? s0 : (s == 1) ? s1 : s2;
  wtp[s*16384 + c*128 + r] = src[li];
}

// ---------------- pack weights into bf16 MFMA B-fragment order -------------
// dst layout: [ct][kc][lane(64)][j(8)], ct=n/16, kc=k/32, lane=(n%16)+16*((k%32)/8), j=k%8
__global__ __launch_bounds__(256) void k_pack(
    const float* __restrict__ s0, const float* __restrict__ s1,
    unsigned short* __restrict__ dst, int K, int NC, int nsplit,
    int s0bs, int s1bs, int dstbs)
{
  int id = blockIdx.x*256 + threadIdx.x;
  if (id >= K*NC) return;
  int by = blockIdx.y;
  int n = id / K, k = id - n*K;
  float v = (n < nsplit) ? s0[(size_t)by*s0bs + (size_t)n*K + k]
                         : s1[(size_t)by*s1bs + (size_t)(n-nsplit)*K + k];
  int ct = n >> 4, kc = k >> 5;
  int lane = (n & 15) | (((k >> 3) & 3) << 4);
  int j = k & 7;
  int KC = K >> 5;
  dst[(size_t)by*dstbs + (((size_t)ct*KC + kc)*64 + lane)*8 + j] = f2bu(v);
}

// ---------------- VSN per-feature GRN (MFMA) -> proc2 chunk-major bf16 -----
__global__ __launch_bounds__(256) void k_vsn_mfma(
    const float* __restrict__ x, const float* __restrict__ fc1_w, const float* __restrict__ fc1_b,
    const unsigned short* __restrict__ pk, const float* __restrict__ fc2_b,
    const float* __restrict__ gate_b, const float* __restrict__ skip_w,
    const float* __restrict__ skip_b, const float* __restrict__ ln_g,
    const float* __restrict__ ln_b, unsigned short* __restrict__ proc2)
{
  const int f = blockIdx.y;
  const int nb = blockIdx.x;
  const int n0 = nb * 64;
  const int tid = threadIdx.x;
  const int wv = tid >> 6, l = tid & 63;
  __shared__ __align__(16) unsigned short As[64*136];
  __shared__ float xs[64];
  __shared__ float vbuf[64*129];
  __shared__ float red[64][4][2];
  __shared__ float mr[64][2];
  if (tid < 64) xs[tid] = x[(size_t)(n0+tid)*9 + f];
  __syncthreads();
  { int i = tid & 127;
    float w1 = fc1_w[f*128 + i], b1 = fc1_b[f*128 + i];
    for (int it = 0; it < 32; it++) {
      int tk = (tid >> 7) + it*2;
      As[tk*136 + i] = f2bu(eluf(xs[tk]*w1 + b1));
    }
  }
  __syncthreads();
  const unsigned short* Wp = pk + PK_VSN + (size_t)f*32768;
  f32x4 acc[4][4];
  #pragma unroll
  for (int rt = 0; rt < 4; rt++)
    #pragma unroll
    for (int ci = 0; ci < 4; ci++) acc[rt][ci] = (f32x4)(0.f);
  #pragma unroll
  for (int kc = 0; kc < 4; kc++) {
    short8 af[4];
    #pragma unroll
    for (int rt = 0; rt < 4; rt++) {
      int row = rt*16 + (l & 15), g = kc*4 + (l >> 4);
      af[rt] = *(const short8*)&As[row*136 + g*8];
    }
    short8 bf[4];
    #pragma unroll
    for (int ci = 0; ci < 4; ci++) {
      int ct = (ci < 2) ? (wv*2 + ci) : (8 + wv*2 + (ci-2));
      bf[ci] = *(const short8*)&Wp[(((size_t)ct*4 + kc)*64 + l)*8];
    }
    #pragma unroll
    for (int rt = 0; rt < 4; rt++)
      #pragma unroll
      for (int ci = 0; ci < 4; ci++)
        acc[rt][ci] = __builtin_amdgcn_mfma_f32_16x16x32_bf16(af[rt], bf[ci], acc[rt][ci], 0, 0, 0);
  }
  __syncthreads();
  #pragma unroll
  for (int ci = 0; ci < 2; ci++) {
    int ch = wv*32 + ci*16 + (l & 15);
    float fb = fc2_b[f*128 + ch], gb = gate_b[f*128 + ch];
    float sw = skip_w[f*128 + ch], sb = skip_b[f*128 + ch];
    #pragma unroll
    for (int rt = 0; rt < 4; rt++)
      #pragma unroll
      for (int r = 0; r < 4; r++) {
        int row = rt*16 + (l >> 4)*4 + r;
        float hv = acc[rt][ci][r] + fb;
        float gv = sigm(acc[rt][ci+2][r] + gb);
        float sv = xs[row]*sw + sb;
        vbuf[row*129 + ch] = sv + hv*gv;
      }
  }
  __syncthreads();
  { int tk = tid >> 2, q = tid & 3;
    float s1 = 0.f, s2 = 0.f;
    #pragma unroll
    for (int i = 0; i < 32; i++) { float z = vbuf[tk*129 + q*32 + i]; s1 += z; s2 += z*z; }
    red[tk][q][0] = s1; red[tk][q][1] = s2;
  }
  __syncthreads();
  if ((tid & 3) == 0) {
    int tk = tid >> 2;
    float a = 0.f, b2 = 0.f;
    for (int p = 0; p < 4; p++) { a += red[tk][p][0]; b2 += red[tk][p][1]; }
    float mean = a * 0.0078125f;
    float var = b2 * 0.0078125f - mean*mean;
    mr[tk][0] = mean; mr[tk][1] = rsqrtf(fmaxf(var, 0.f) + 1e-5f);
  }
  __syncthreads();
  { int i = tid & 127;
    float lg = ln_g[f*128 + i], lb = ln_b[f*128 + i];
    size_t base = ((size_t)nb*9 + f)*8192;
    for (int it = 0; it < 32; it++) {
      int tk = (tid >> 7) + it*2;
      float z = (vbuf[tk*129 + i] - mr[tk][0]) * mr[tk][1] * lg + lb;
      proc2[base + tk*128 + i] = f2bu(z);
    }
  }
}

// ---------------- grand-selection GRN (MFMA, fully fused) -> sel bf16 ------
__global__ __launch_bounds__(256) void k_gc_mfma(
    const unsigned short* __restrict__ proc2, const unsigned short* __restrict__ pk,
    const float* __restrict__ fc1_b, const float* __restrict__ fc2_b,
    const float* __restrict__ gate_b, const float* __restrict__ skip_b,
    const float* __restrict__ ln_g, const float* __restrict__ ln_b,
    unsigned short* __restrict__ selb)
{
  const int nb = blockIdx.x;
  const int n0 = nb * 64;
  const int tid = threadIdx.x;
  const int wv = tid >> 6, l = tid & 63;
  __shared__ __align__(16) unsigned short As[64*136];
  __shared__ __align__(16) unsigned short A2s[64*136];
  __shared__ float vbuf[64*129];
  __shared__ float red[64][4][2];
  __shared__ float mr[64][2];
  const unsigned short* W1 = pk + PK_GC1;
  f32x4 acc1[4][4];
  #pragma unroll
  for (int rt = 0; rt < 4; rt++)
    #pragma unroll
    for (int ci = 0; ci < 4; ci++) acc1[rt][ci] = (f32x4)(0.f);
  for (int c = 0; c < 9; c++) {
    size_t cbase = ((size_t)nb*9 + c)*8192;
    #pragma unroll
    for (int i = 0; i < 4; i++) {
      int gi = i*256 + tid;
      int row = gi >> 4, g = gi & 15;
      uint4 v = *(const uint4*)(proc2 + cbase + row*128 + g*8);
      *(uint4*)&As[row*136 + g*8] = v;
    }
    __syncthreads();
    #pragma unroll
    for (int kc = 0; kc < 4; kc++) {
      int kk = c*4 + kc;
      short8 af[4];
      #pragma unroll
      for (int rt = 0; rt < 4; rt++) {
        int row = rt*16 + (l & 15), g = kc*4 + (l >> 4);
        af[rt] = *(const short8*)&As[row*136 + g*8];
      }
      short8 bf[4];
      #pragma unroll
      for (int ci = 0; ci < 4; ci++) {
        int ct = (ci < 2) ? (wv*2 + ci) : (8 + wv*2 + (ci-2));
        bf[ci] = *(const short8*)&W1[(((size_t)ct*36 + kk)*64 + l)*8];
      }
      #pragma unroll
      for (int rt = 0; rt < 4; rt++)
        #pragma unroll
        for (int ci = 0; ci < 4; ci++)
          acc1[rt][ci] = __builtin_amdgcn_mfma_f32_16x16x32_bf16(af[rt], bf[ci], acc1[rt][ci], 0, 0, 0);
    }
    __syncthreads();
  }
  #pragma unroll
  for (int ci = 0; ci < 2; ci++) {
    int ch = wv*32 + ci*16 + (l & 15);
    float fb = fc1_b[ch];
    #pragma unroll
    for (int rt = 0; rt < 4; rt++)
      #pragma unroll
      for (int r = 0; r < 4; r++) {
        int row = rt*16 + (l >> 4)*4 + r;
        A2s[row*136 + ch] = f2bu(eluf(acc1[rt][ci][r] + fb));
      }
  }
  __syncthreads();
  const unsigned short* W2 = pk + PK_GC2;
  f32x4 acc2[4][4];
  #pragma unroll
  for (int rt = 0; rt < 4; rt++)
    #pragma unroll
    for (int ci = 0; ci < 4; ci++) acc2[rt][ci] = (f32x4)(0.f);
  #pragma unroll
  for (int kc = 0; kc < 4; kc++) {
    short8 af[4];
    #pragma unroll
    for (int rt = 0; rt < 4; rt++) {
      int row = rt*16 + (l & 15), g = kc*4 + (l >> 4);
      af[rt] = *(const short8*)&A2s[row*136 + g*8];
    }
    short8 bf[4];
    #pragma unroll
    for (int ci = 0; ci < 4; ci++) {
      int ct = (ci < 2) ? (wv*2 + ci) : (8 + wv*2 + (ci-2));
      bf[ci] = *(const short8*)&W2[(((size_t)ct*4 + kc)*64 + l)*8];
    }
    #pragma unroll
    for (int rt = 0; rt < 4; rt++)
      #pragma unroll
      for (int ci = 0; ci < 4; ci++)
        acc2[rt][ci] = __builtin_amdgcn_mfma_f32_16x16x32_bf16(af[rt], bf[ci], acc2[rt][ci], 0, 0, 0);
  }
  __syncthreads();
  #pragma unroll
  for (int ci = 0; ci < 2; ci++) {
    int ch = wv*32 + ci*16 + (l & 15);
    float f2 = fc2_b[ch], gb = gate_b[ch], sb = skip_b[ch];
    #pragma unroll
    for (int rt = 0; rt < 4; rt++)
      #pragma unroll
      for (int r = 0; r < 4; r++) {
        int row = rt*16 + (l >> 4)*4 + r;
        float hv = acc2[rt][ci][r] + f2;
        float gv = sigm(acc2[rt][ci+2][r] + gb);
        float sv = acc1[rt][ci+2][r] + sb;
        vbuf[row*129 + ch] = sv + hv*gv;
      }
  }
  __syncthreads();
  { int tk = tid >> 2, q = tid & 3;
    float s1 = 0.f, s2 = 0.f;
    #pragma unroll
    for (int i = 0; i < 32; i++) { float z = vbuf[tk*129 + q*32 + i]; s1 += z; s2 += z*z; }
    red[tk][q][0] = s1; red[tk][q][1] = s2;
  }
  __syncthreads();
  if ((tid & 3) == 0) {
    int tk = tid >> 2;
    float a = 0.f, b2 = 0.f;
    for (int p = 0; p < 4; p++) { a += red[tk][p][0]; b2 += red[tk][p][1]; }
    float mean = a * 0.0078125f;
    float var = b2 * 0.0078125f - mean*mean;
    mr[tk][0] = mean; mr[tk][1] = rsqrtf(fmaxf(var, 0.f) + 1e-5f);
  }
  __syncthreads();
  { int i = tid & 127;
    float lg = ln_g[i], lb = ln_b[i];
    for (int it = 0; it < 32; it++) {
      int tk = (tid >> 7) + it*2;
      float z = (vbuf[tk*129 + i] - mr[tk][0]) * mr[tk][1] * lg + lb;
      selb[(size_t)(n0+tk)*128 + i] = f2bu(z);
    }
  }
}

// ---------------- generic bf16 MFMA GEMM, out fp32 or f16 ------------------
__global__ __launch_bounds__(256) void k_mm(
    const unsigned short* __restrict__ A, const unsigned short* __restrict__ Wp,
    const float* __restrict__ b0, const float* __restrict__ b1,
    void* __restrict__ out, int out_ld, int outmode)
{
  const int r0 = blockIdx.x * 64;
  const int cb = blockIdx.y * 128;
  const int tid = threadIdx.x;
  const int wv = tid >> 6, l = tid & 63;
  __shared__ __align__(16) unsigned short As[64*136];
  #pragma unroll
  for (int i = 0; i < 4; i++) {
    int gi = i*256 + tid;
    int row = gi >> 4, g = gi & 15;
    uint4 v = *(const uint4*)(A + (size_t)(r0+row)*128 + g*8);
    *(uint4*)&As[row*136 + g*8] = v;
  }
  __syncthreads();
  f32x4 acc[4][2];
  #pragma unroll
  for (int rt = 0; rt < 4; rt++)
    #pragma unroll
    for (int ci = 0; ci < 2; ci++) acc[rt][ci] = (f32x4)(0.f);
  #pragma unroll
  for (int kc = 0; kc < 4; kc++) {
    short8 af[4];
    #pragma unroll
    for (int rt = 0; rt < 4; rt++) {
      int row = rt*16 + (l & 15), g = kc*4 + (l >> 4);
      af[rt] = *(const short8*)&As[row*136 + g*8];
    }
    short8 bf[2];
    #pragma unroll
    for (int ci = 0; ci < 2; ci++) {
      int ct = (cb >> 4) + wv*2 + ci;
      bf[ci] = *(const short8*)&Wp[(((size_t)ct*4 + kc)*64 + l)*8];
    }
    #pragma unroll
    for (int rt = 0; rt < 4; rt++)
      #pragma unroll
      for (int ci = 0; ci < 2; ci++)
        acc[rt][ci] = __builtin_amdgcn_mfma_f32_16x16x32_bf16(af[rt], bf[ci], acc[rt][ci], 0, 0, 0);
  }
  #pragma unroll
  for (int ci = 0; ci < 2; ci++) {
    int cl = cb + wv*32 + ci*16 + (l & 15);
    float bias = b0[cl] + (b1 ? b1[cl] : 0.f);
    #pragma unroll
    for (int rt = 0; rt < 4; rt++)
      #pragma unroll
      for (int r = 0; r < 4; r++) {
        int row = r0 + rt*16 + (l >> 4)*4 + r;
        float v = acc[rt][ci][r] + bias;
        if (outmode == 0) ((float*)out)[(size_t)row*out_ld + cl] = v;
        else ((unsigned short*)out)[(size_t)row*out_ld + cl] = f2h(v);
      }
  }
}

// ---------------- fused 2-layer LSTM scan, software-pipelined --------------
// 768 threads: [0,256) whh0 matvec (+act-l0 on [0,128)); [256,512) wih1 matvec;
// [512,768) whh1 matvec (+act-l1 on [512,640)). f16 dot2 math, fp32 accum/state.
// amdgpu_num_vgpr(168): direct VGPR request (= 3 waves/SIMD). r6-r8 evidence:
// both __launch_bounds__(768,3) and amdgpu_waves_per_eu(3,3) were no-ops --
// allocator stuck at 84 VGPR (2-blocks/CU target), spilling w0/w1 (WRITE_SIZE
// 101 MB = exactly 768thr*256blk*512B) and re-reading ~393 KB/CU/step from L2
// => 490+ us. Runtime occupancy is 1 block/CU anyway (35.8% = 12/32 waves),
// so the 2-block target wastes nothing by being dropped.
__global__ __attribute__((amdgpu_flat_work_group_size(768, 768), amdgpu_num_vgpr(168)))
void k_lstm2(
    const unsigned short* __restrict__ pre0,  // f16 [B][T][512] (tstr=512) or [B][512] (tstr=0)
    const float* __restrict__ whh0, const float* __restrict__ wih1,
    const float* __restrict__ whh1,
    const float* __restrict__ bih1, const float* __restrict__ bhh1,
    const float* __restrict__ h0i, const float* __restrict__ c0i,
    const float* __restrict__ h1i, const float* __restrict__ c1i,
    int T, int tstr,
    unsigned short* __restrict__ ys1,         // bf16 [B][T][128]
    float* __restrict__ h0T, float* __restrict__ c0T,
    float* __restrict__ h1T, float* __restrict__ c1T,
    unsigned short* __restrict__ h1Tb)        // bf16 [B][128]
{
  const int b = blockIdx.x, tid = threadIdx.x;
  __shared__ __align__(16) unsigned short h0h[128];
  __shared__ __align__(16) unsigned short h1h[128];
  __shared__ float rec0[512];
  __shared__ float pin1[512];
  __shared__ float rec1[512];
  unsigned int w0[64], w1[64];
  {
    const float* Ws; int r;
    if (tid < 256)      { Ws = whh0; r = tid; }
    else if (tid < 512) { Ws = wih1; r = tid - 256; }
    else                { Ws = whh1; r = tid - 512; }
    const float* p0 = Ws + (size_t)r*128;
    const float* p1 = Ws + (size_t)(r+256)*128;
    #pragma unroll
    for (int k = 0; k < 64; k++) {
      w0[k] = pkh(p0[2*k], p0[2*k+1]);
      w1[k] = pkh(p1[2*k], p1[2*k+1]);
    }
  }
  float c0 = 0.f, c1 = 0.f;
  float bbi = 0.f, bbf = 0.f, bbg = 0.f, bbo = 0.f;
  if (tid < 128) {
    float h = h0i ? h0i[(size_t)b*128 + tid] : 0.f;
    c0 = c0i ? c0i[(size_t)b*128 + tid] : 0.f;
    h0h[tid] = f2h(h);
  }
  if (tid >= 512 && tid < 640) {
    int j = tid - 512;
    float h = h1i ? h1i[(size_t)b*128 + j] : 0.f;
    c1 = c1i ? c1i[(size_t)b*128 + j] : 0.f;
    h1h[j] = f2h(h);
    bbi = bih1[j]       + bhh1[j];
    bbf = bih1[128 + j] + bhh1[128 + j];
    bbg = bih1[256 + j] + bhh1[256 + j];
    bbo = bih1[384 + j] + bhh1[384 + j];
  }
  __syncthreads();
  const unsigned short* preb = pre0 + (size_t)b * (tstr ? (size_t)T*tstr : 512);
  for (int i = 0; i <= T; i++) {
    // early-issue layer-0 pre loads for step i (consumed after matvec barrier)
    unsigned short ru_i = 0, ru_f = 0, ru_g = 0, ru_o = 0;
    if (i < T && tid < 128) {
      const unsigned short* pt = preb + (size_t)i*tstr;
      ru_i = pt[tid]; ru_f = pt[128 + tid];
      ru_g = pt[256 + tid]; ru_o = pt[384 + tid];
    }
    // matvecs (A idle at i==T)
    if (i < T || tid >= 256) {
      const unsigned short* hsrc = (tid < 512) ? h0h : h1h;
      float a0[4] = {0.f,0.f,0.f,0.f}, a1[4] = {0.f,0.f,0.f,0.f};
      #pragma unroll
      for (int k4 = 0; k4 < 16; k4++) {
        uint4 hh = *(const uint4*)&hsrc[k4*8];
        a0[0] = fd2(w0[4*k4+0], hh.x, a0[0]);
        a0[1] = fd2(w0[4*k4+1], hh.y, a0[1]);
        a0[2] = fd2(w0[4*k4+2], hh.z, a0[2]);
        a0[3] = fd2(w0[4*k4+3], hh.w, a0[3]);
        a1[0] = fd2(w1[4*k4+0], hh.x, a1[0]);
        a1[1] = fd2(w1[4*k4+1], hh.y, a1[1]);
        a1[2] = fd2(w1[4*k4+2], hh.z, a1[2]);
        a1[3] = fd2(w1[4*k4+3], hh.w, a1[3]);
      }
      float s0 = (a0[0]+a0[1]) + (a0[2]+a0[3]);
      float s1 = (a1[0]+a1[1]) + (a1[2]+a1[3]);
      float* dst = (tid < 256) ? rec0 : (tid < 512 ? pin1 : rec1);
      int r = tid & 255;
      dst[r] = s0; dst[r + 256] = s1;
    }
    __syncthreads();
    if (i < T && tid < 128) {
      float gi = sigm (h2f(ru_i) + rec0[tid]);
      float gf = sigm (h2f(ru_f) + rec0[128 + tid]);
      float gg = tanhx(h2f(ru_g) + rec0[256 + tid]);
      float go = sigm (h2f(ru_o) + rec0[384 + tid]);
      c0 = gf*c0 + gi*gg;
      float h = go * tanhx(c0);
      h0h[tid] = f2h(h);
      if (i == T-1) { h0T[(size_t)b*128 + tid] = h; c0T[(size_t)b*128 + tid] = c0; }
    }
    if (i >= 1 && tid >= 512 && tid < 640) {
      int j = tid - 512, t = i - 1;
      float gi = sigm (pin1[j]       + rec1[j]       + bbi);
      float gf = sigm (pin1[128 + j] + rec1[128 + j] + bbf);
      float gg = tanhx(pin1[256 + j] + rec1[256 + j] + bbg);
      float go = sigm (pin1[384 + j] + rec1[384 + j] + bbo);
      c1 = gf*c1 + gi*gg;
      float h = go * tanhx(c1);
      h1h[j] = f2h(h);
      ys1[((size_t)b*T + t)*128 + j] = f2bu(h);
      if (t == T-1) {
        h1T[(size_t)b*128 + j] = h; c1T[(size_t)b*128 + j] = c1;
        h1Tb[(size_t)b*128 + j] = f2bu(h);
      }
    }
    __syncthreads();
  }
}

// ---------------- cross attention: one block per (batch, head) -------------
__global__ __launch_bounds__(256) void k_attn(
    const float* __restrict__ Q, const float* __restrict__ K, const float* __restrict__ V,
    unsigned short* __restrict__ o)
{
  const int b = blockIdx.x, h = blockIdx.y, tid = threadIdx.x;
  __shared__ float Ks[168][33];
  __shared__ float Vs[168][32];
  __shared__ float Qs[24][32];
  __shared__ float Sc[24][169];
  __shared__ float red[24][8];
  __shared__ float rowm[24], rows[24];
  for (int e = tid; e < 168*32; e += 256) {
    int t = e >> 5, d = e & 31;
    Ks[t][d] = K[((size_t)b*168 + t)*128 + h*32 + d];
    Vs[t][d] = V[((size_t)b*168 + t)*128 + h*32 + d];
  }
  for (int e = tid; e < 24*32; e += 256) {
    int q = e >> 5, d = e & 31;
    Qs[q][d] = Q[((size_t)b*24 + q)*128 + h*32 + d];
  }
  __syncthreads();
  for (int e = tid; e < 24*168; e += 256) {
    int q = e / 168, t = e - q*168;
    float s = 0.f;
    #pragma unroll
    for (int d = 0; d < 32; d++) s += Qs[q][d]*Ks[t][d];
    Sc[q][t] = s * 0.17677669529663687f;
  }
  __syncthreads();
  int q = tid >> 3, l8 = tid & 7;
  if (q < 24) {
    float m = -1e30f;
    for (int t = l8; t < 168; t += 8) m = fmaxf(m, Sc[q][t]);
    red[q][l8] = m;
  }
  __syncthreads();
  if (q < 24 && l8 == 0) {
    float m = red[q][0];
    for (int p = 1; p < 8; p++) m = fmaxf(m, red[q][p]);
    rowm[q] = m;
  }
  __syncthreads();
  if (q < 24) {
    float s = 0.f;
    for (int t = l8; t < 168; t += 8) {
      float e2 = __expf(Sc[q][t] - rowm[q]);
      Sc[q][t] = e2; s += e2;
    }
    red[q][l8] = s;
  }
  __syncthreads();
  if (q < 24 && l8 == 0) {
    float s = 0.f;
    for (int p = 0; p < 8; p++) s += red[q][p];
    rows[q] = 1.f/s;
  }
  __syncthreads();
  for (int e = tid; e < 24*32; e += 256) {
    int qq = e >> 5, d = e & 31;
    float acc = 0.f;
    for (int t = 0; t < 168; t++) acc += Sc[qq][t]*Vs[t][d];
    o[((size_t)b*24 + qq)*128 + h*32 + d] = f2bu(acc * rows[qq]);
  }
}

// ---------------- post-attention GRN (identity skip), 32 tokens/block ------
__global__ __launch_bounds__(256) void k_pa_grn(
    const float* __restrict__ xin, const float* __restrict__ wt,
    const float* __restrict__ fc1_b, const float* __restrict__ fc2_b,
    const float* __restrict__ gate_b, const float* __restrict__ ln_g,
    const float* __restrict__ ln_b, float* __restrict__ out)
{
  const int n0 = blockIdx.x * 32;
  const int tid = threadIdx.x;
  __shared__ float xs[32][130];
  __shared__ float h1[32][130];
  __shared__ float red[32][8][2];
  __shared__ float mr[32][2];
  for (int t4 = tid; t4 < 1024; t4 += 256) {
    int r = t4 >> 5, c = (t4 & 31) << 2;
    float4 v = *(const float4*)(xin + (size_t)(n0 + r)*128 + c);
    xs[r][c] = v.x; xs[r][c+1] = v.y; xs[r][c+2] = v.z; xs[r][c+3] = v.w;
  }
  __syncthreads();
  const int oo = tid & 15, tt = tid >> 4;
  const float* fc1t = wt + OFF_PA_FC1T;
  {
    float af[2][8];
    #pragma unroll
    for (int j = 0; j < 2; j++)
      #pragma unroll
      for (int c = 0; c < 8; c++) af[j][c] = 0.f;
    for (int k = 0; k < 128; k++) {
      float4 wa = *(const float4*)(fc1t + k*128 + oo*4);
      float4 wb = *(const float4*)(fc1t + k*128 + 64 + oo*4);
      float wv[8] = {wa.x,wa.y,wa.z,wa.w,wb.x,wb.y,wb.z,wb.w};
      #pragma unroll
      for (int j = 0; j < 2; j++) {
        float a = xs[tt*2+j][k];
        #pragma unroll
        for (int c = 0; c < 8; c++) af[j][c] += a*wv[c];
      }
    }
    #pragma unroll
    for (int j = 0; j < 2; j++) {
      int tk = tt*2 + j;
      #pragma unroll
      for (int c = 0; c < 8; c++) {
        int col = (c < 4) ? (oo*4 + c) : (64 + oo*4 + (c-4));
        h1[tk][col] = eluf(af[j][c] + fc1_b[col]);
      }
    }
  }
  __syncthreads();
  const float* fc2t = wt + OFF_PA_FC2T;
  const float* gtt  = wt + OFF_PA_GATET;
  float ah[2][8], ag[2][8];
  #pragma unroll
  for (int j = 0; j < 2; j++)
    #pragma unroll
    for (int c = 0; c < 8; c++) { ah[j][c] = 0.f; ag[j][c] = 0.f; }
  for (int k = 0; k < 128; k++) {
    float4 wa = *(const float4*)(fc2t + k*128 + oo*4);
    float4 wb = *(const float4*)(fc2t + k*128 + 64 + oo*4);
    float4 wc = *(const float4*)(gtt + k*128 + oo*4);
    float4 wd = *(const float4*)(gtt + k*128 + 64 + oo*4);
    float whv[8] = {wa.x,wa.y,wa.z,wa.w,wb.x,wb.y,wb.z,wb.w};
    float wgv[8] = {wc.x,wc.y,wc.z,wc.w,wd.x,wd.y,wd.z,wd.w};
    #pragma unroll
    for (int j = 0; j < 2; j++) {
      float a = h1[tt*2+j][k];
      #pragma unroll
      for (int c = 0; c < 8; c++) { ah[j][c] += a*whv[c]; ag[j][c] += a*wgv[c]; }
    }
  }
  __syncthreads();
  #pragma unroll
  for (int j = 0; j < 2; j++) {
    int tk = tt*2 + j;
    #pragma unroll
    for (int c = 0; c < 8; c++) {
      int col = (c < 4) ? (oo*4 + c) : (64 + oo*4 + (c-4));
      float hv = ah[j][c] + fc2_b[col];
      float gv = sigm(ag[j][c] + gate_b[col]);
      xs[tk][col] = xs[tk][col] + hv*gv;
    }
  }
  __syncthreads();
  { int tk = tid >> 3, qq = tid & 7;
    float s1 = 0.f, s2 = 0.f;
    #pragma unroll
    for (int i = 0; i < 16; i++) { float z = xs[tk][qq*16+i]; s1 += z; s2 += z*z; }
    red[tk][qq][0] = s1; red[tk][qq][1] = s2;
  }
  __syncthreads();
  if ((tid & 7) == 0) {
    int tk = tid >> 3;
    float a = 0.f, b2 = 0.f;
    for (int p = 0; p < 8; p++) { a += red[tk][p][0]; b2 += red[tk][p][1]; }
    float mean = a * 0.0078125f;
    float var = b2 * 0.0078125f - mean*mean;
    mr[tk][0] = mean; mr[tk][1] = rsqrtf(fmaxf(var, 0.f) + 1e-5f);
  }
  __syncthreads();
  for (int e = tid; e < 32*128; e += 256) {
    int r = e >> 7, c = e & 127;
    out[(size_t)(n0+r)*128 + c] = (xs[r][c] - mr[r][0]) * mr[r][1] * ln_g[c] + ln_b[c];
  }
}

// ---------------- final projection 128 -> 6 --------------------------------
__global__ __launch_bounds__(256) void k_final(
    const float* __restrict__ a, const float* __restrict__ fo_w,
    const float* __restrict__ fo_b, float* __restrict__ out)
{
  int idx = blockIdx.x*256 + threadIdx.x;
  if (idx >= NDTOK*6) return;
  int n = idx / 6, j = idx - n*6;
  const float* ar = a + (size_t)n*128;
  const float* w = fo_w + j*128;
  float s = fo_b[j];
  #pragma unroll 4
  for (int d = 0; d < 128; d++) s += ar[d]*w[d];
  out[idx] = s;
}

extern "C" void kernel_launch(void* const* d_in, const int* in_sizes, int n_in,
                              void* d_out, int out_size, void* d_ws, size_t ws_size,
                              hipStream_t stream) {
  (void)in_sizes; (void)n_in; (void)out_size; (void)ws_size;
  const float* x      = (const float*)d_in[0];
  const float* vfc1w  = (const float*)d_in[1];
  const float* vfc1b  = (const float*)d_in[2];
  const float* vfc2w  = (const float*)d_in[3];
  const float* vfc2b  = (const float*)d_in[4];
  const float* vgw    = (const float*)d_in[5];
  const float* vgb    = (const float*)d_in[6];
  const float* vskw   = (const float*)d_in[7];
  const float* vskb   = (const float*)d_in[8];
  const float* vlng   = (const float*)d_in[9];
  const float* vlnb   = (const float*)d_in[10];
  const float* gfc1w  = (const float*)d_in[11];
  const float* gfc1b  = (const float*)d_in[12];
  const float* gfc2w  = (const float*)d_in[13];
  const float* gfc2b  = (const float*)d_in[14];
  const float* ggw    = (const float*)d_in[15];
  const float* ggb    = (const float*)d_in[16];
  const float* gskw   = (const float*)d_in[17];
  const float* gskb   = (const float*)d_in[18];
  const float* glng   = (const float*)d_in[19];
  const float* glnb   = (const float*)d_in[20];
  const float* encwih = (const float*)d_in[21];
  const float* encwhh = (const float*)d_in[22];
  const float* encbih = (const float*)d_in[23];
  const float* encbhh = (const float*)d_in[24];
  const float* decwih = (const float*)d_in[25];
  const float* decwhh = (const float*)d_in[26];
  const float* decbih = (const float*)d_in[27];
  const float* decbhh = (const float*)d_in[28];
  const float* ainw   = (const float*)d_in[29];
  const float* ainb   = (const float*)d_in[30];
  const float* aoutw  = (const float*)d_in[31];
  const float* aoutb  = (const float*)d_in[32];
  const float* pfc1w  = (const float*)d_in[33];
  const float* pfc1b  = (const float*)d_in[34];
  const float* pfc2w  = (const float*)d_in[35];
  const float* pfc2b  = (const float*)d_in[36];
  const float* pgw    = (const float*)d_in[37];
  const float* pgb    = (const float*)d_in[38];
  const float* plng   = (const float*)d_in[39];
  const float* plnb   = (const float*)d_in[40];
  const float* fow    = (const float*)d_in[41];
  const float* fob    = (const float*)d_in[42];

  float* ws = (float*)d_ws;
  // ---- workspace (float offsets), sizes verified:
  //   bf16/f16 [43008,128] = 2,752,512 fl; f16 [43008,512] = 11,010,048 fl;
  //   proc2 bf16 [672*9*64*128] = 24,772,608 fl.
  float* wtp = ws;                                        // [0, 49,152)
  unsigned short* pk = (unsigned short*)(ws + 50000);     // [50,000, 459,600)
  unsigned short* proc2 = (unsigned short*)(ws + 500000); // [500,000, 25,272,608)
  unsigned short* pre = (unsigned short*)(ws + 500000);   // f16 [43008][512] alias (proc2 dead) -> 11,510,048
  float* Kb   = ws + 500000;                              // f32 [43008,128] (pre dead) -> 6,005,024
  float* Vb   = ws + 6100000;                             // -> 11,605,024
  float* Qb   = ws + 12000000;                            // -> 12,786,432
  unsigned short* attb = (unsigned short*)(ws + 13000000);// -> 13,393,216
  float* ato  = ws + 14000000;                            // -> 14,786,432
  float* pao  = ws + 15000000;                            // -> 15,786,432
  unsigned short* pd0 = (unsigned short*)(ws + 16000000); // f16 [256,512] -> 16,065,536
  unsigned short* selb  = (unsigned short*)(ws + 25300000); // bf16 [43008,128] -> 28,052,512
  unsigned short* encob = (unsigned short*)(ws + 28100000); // bf16 [43008,128] -> 30,852,512
  unsigned short* dout2b = (unsigned short*)(ws + 30900000);// bf16 [6144,128] -> 31,096,608
  float* hT0  = ws + 31300000;  float* cT0 = ws + 31340000;
  float* hT1  = ws + 31380000;  float* cT1 = ws + 31420000;
  unsigned short* hT1b = (unsigned short*)(ws + 31460000);
  float* dscr = ws + 31500000;  // decoder dummy hT/cT outputs + bf16 scratch

  // 1. PA-GRN fp32 transposes
  k_transpose3<<<dim3(192), dim3(256), 0, stream>>>(wtp, pfc1w, pfc2w, pgw);
  // 2. pack bf16 MFMA fragments
  k_pack<<<dim3(128, 9), dim3(256), 0, stream>>>(vfc2w, vgw, pk + PK_VSN, 128, 256, 128, 16384, 16384, 32768);
  k_pack<<<dim3(1152), dim3(256), 0, stream>>>(gfc1w, gskw, pk + PK_GC1, 1152, 256, 128, 0, 0, 0);
  k_pack<<<dim3(128), dim3(256), 0, stream>>>(gfc2w, ggw, pk + PK_GC2, 128, 256, 128, 0, 0, 0);
  k_pack<<<dim3(256), dim3(256), 0, stream>>>(encwih, encwih, pk + PK_ENC0, 128, 512, 512, 0, 0, 0);
  k_pack<<<dim3(256), dim3(256), 0, stream>>>(decwih, decwih, pk + PK_DEC0, 128, 512, 512, 0, 0, 0);
  k_pack<<<dim3(192), dim3(256), 0, stream>>>(ainw, ainw, pk + PK_AIN, 128, 384, 384, 0, 0, 0);
  k_pack<<<dim3(64), dim3(256), 0, stream>>>(aoutw, aoutw, pk + PK_AOUT, 128, 128, 128, 0, 0, 0);
  // 3. VSN per-feature GRNs (MFMA)
  k_vsn_mfma<<<dim3(672, 9), dim3(256), 0, stream>>>(x, vfc1w, vfc1b, pk,
      vfc2b, vgb, vskw, vskb, vlng, vlnb, proc2);
  // 4. grand-selection GRN (MFMA, fused)
  k_gc_mfma<<<dim3(672), dim3(256), 0, stream>>>(proc2, pk, gfc1b, gfc2b, ggb,
      gskb, glng, glnb, selb);
  // 5. encoder layer-0 input projection -> pre (f16)
  k_mm<<<dim3(672, 4), dim3(256), 0, stream>>>(selb, pk + PK_ENC0, encbih, encbhh, pre, 512, 1);
  // 6. fused 2-layer encoder scan
  k_lstm2<<<dim3(256), dim3(768), 0, stream>>>(pre, encwhh, encwih + 65536, encwhh + 65536,
      encbih + 512, encbhh + 512, nullptr, nullptr, nullptr, nullptr,
      TSE, 512, encob, hT0, cT0, hT1, cT1, hT1b);
  // 7. decoder layer-0 input projection (constant input hT1) -> pd0 (f16)
  k_mm<<<dim3(4, 4), dim3(256), 0, stream>>>(hT1b, pk + PK_DEC0, decbih, decbhh, pd0, 512, 1);
  // 8. fused 2-layer decoder scan
  k_lstm2<<<dim3(256), dim3(768), 0, stream>>>(pd0, decwhh, decwih + 65536, decwhh + 65536,
      decbih + 512, decbhh + 512, hT0, cT0, hT1, cT1,
      TSD, 0, dout2b, dscr, dscr + 40000, dscr + 80000, dscr + 120000,
      (unsigned short*)(dscr + 160000));
  // 9. attention projections
  k_mm<<<dim3(96, 1), dim3(256), 0, stream>>>(dout2b, pk + PK_AIN, ainb, nullptr, Qb, 128, 0);
  k_mm<<<dim3(672, 1), dim3(256), 0, stream>>>(encob, pk + PK_AIN + 16384, ainb + 128, nullptr, Kb, 128, 0);
  k_mm<<<dim3(672, 1), dim3(256), 0, stream>>>(encob, pk + PK_AIN + 32768, ainb + 256, nullptr, Vb, 128, 0);
  // 10. attention core
  k_attn<<<dim3(256, 4), dim3(256), 0, stream>>>(Qb, Kb, Vb, attb);
  // 11. attention output projection
  k_mm<<<dim3(96, 1), dim3(256), 0, stream>>>(attb, pk + PK_AOUT, aoutb, nullptr, ato, 128, 0);
  // 12. post-attention GRN
  k_pa_grn<<<dim3(192), dim3(256), 0, stream>>>(ato, wtp, pfc1b, pfc2b, pgb,
      plng, plnb, pao);
  // 13. final projection
  k_final<<<dim3(144), dim3(256), 0, stream>>>(pao, fow, fob, (float*)d_out);
}

// Round 10
// 764.509 us; speedup vs baseline: 1.3587x; 1.3587x over previous
//
#include <hip/hip_runtime.h>
#include <hip/hip_bf16.h>

#define NBATCH 256
#define TSE 168
#define TSD 24
#define NTOK (NBATCH*TSE)   // 43008
#define NDTOK (NBATCH*TSD)  // 6144

// PA-GRN transposed fp32 weights (floats, in wtp region)
#define OFF_PA_FC1T    0
#define OFF_PA_FC2T    16384
#define OFF_PA_GATET   32768

// packed bf16 MFMA-B-fragment offsets (ushort units, region base pk)
#define PK_VSN   0         // 9 x [K=128, NC=256]  = 294912
#define PK_GC1   294912    // [K=1152, NC=256]     = 294912
#define PK_GC2   589824    // [K=128, NC=256]      = 32768
#define PK_ENC0  622592    // [128,512]            = 65536
#define PK_ENC1  688128    // [128,512]            = 65536
#define PK_DEC0  753664    // [128,512]            = 65536
#define PK_DEC1  819200    // [128,512]            = 65536
#define PK_AIN   884736    // [128,384]            = 49152
#define PK_AOUT  933888    // [128,128]            = 16384
// pk total = 950,272 ushorts = 475,136 floats

typedef __attribute__((ext_vector_type(8))) short short8;
typedef __attribute__((ext_vector_type(4))) float f32x4;
typedef __attribute__((ext_vector_type(2))) __fp16 fp16x2;

__device__ __forceinline__ float sigm(float x){ return 1.f/(1.f + __expf(-x)); }
__device__ __forceinline__ float tanhx(float x){
  float cx = fminf(fmaxf(x, -15.f), 15.f);
  float e = __expf(2.f*cx);
  return (e-1.f)/(e+1.f);
}
__device__ __forceinline__ float eluf(float x){ return x > 0.f ? x : (__expf(x)-1.f); }
__device__ __forceinline__ unsigned short f2bu(float v){
  unsigned int u = __float_as_uint(v);
  u = (u + 0x7fffu + ((u>>16)&1u)) >> 16;
  return (unsigned short)u;
}
__device__ __forceinline__ unsigned int pkh(float a, float b){
  union { fp16x2 h; unsigned int u; } v;
  v.h = __builtin_amdgcn_cvt_pkrtz(a, b);
  return v.u;
}
__device__ __forceinline__ unsigned short f2h(float x){
  union { _Float16 h; unsigned short u; } v;
  v.h = (_Float16)x; return v.u;
}
__device__ __forceinline__ float h2f(unsigned short u){
  union { unsigned short u; _Float16 h; } v;
  v.u = u; return (float)v.h;
}
__device__ __forceinline__ float fd2(unsigned int a, unsigned int b, float c){
  union { unsigned int u; fp16x2 h; } ua, ub;
  ua.u = a; ub.u = b;
  return __builtin_amdgcn_fdot2(ua.h, ub.h, c, false);
}

// ---------------- transpose 3 PA 128x128 fp32 weights ----------------------
__global__ __launch_bounds__(256) void k_transpose3(float* __restrict__ wtp,
    const float* s0, const float* s1, const float* s2)
{
  int idx = blockIdx.x*256 + threadIdx.x;
  if (idx >= 49152) return;
  int s = idx >> 14, li = idx & 16383;
  int r = li >> 7, c = li & 127;
  const float* src = (s == 0) ? s0 : (s == 1) ? s1 : s2;
  wtp[s*16384 + c*128 + r] = src[li];
}

// ---------------- pack weights into bf16 MFMA B-fragment order -------------
// dst layout: [ct][kc][lane(64)][j(8)], ct=n/16, kc=k/32, lane=(n%16)+16*((k%32)/8), j=k%8
__global__ __launch_bounds__(256) void k_pack(
    const float* __restrict__ s0, const float* __restrict__ s1,
    unsigned short* __restrict__ dst, int K, int NC, int nsplit,
    int s0bs, int s1bs, int dstbs)
{
  int id = blockIdx.x*256 + threadIdx.x;
  if (id >= K*NC) return;
  int by = blockIdx.y;
  int n = id / K, k = id - n*K;
  float v = (n < nsplit) ? s0[(size_t)by*s0bs + (size_t)n*K + k]
                         : s1[(size_t)by*s1bs + (size_t)(n-nsplit)*K + k];
  int ct = n >> 4, kc = k >> 5;
  int lane = (n & 15) | (((k >> 3) & 3) << 4);
  int j = k & 7;
  int KC = K >> 5;
  dst[(size_t)by*dstbs + (((size_t)ct*KC + kc)*64 + lane)*8 + j] = f2bu(v);
}

// ---------------- VSN per-feature GRN (MFMA) -> proc2 chunk-major bf16 -----
__global__ __launch_bounds__(256) void k_vsn_mfma(
    const float* __restrict__ x, const float* __restrict__ fc1_w, const float* __restrict__ fc1_b,
    const unsigned short* __restrict__ pk, const float* __restrict__ fc2_b,
    const float* __restrict__ gate_b, const float* __restrict__ skip_w,
    const float* __restrict__ skip_b, const float* __restrict__ ln_g,
    const float* __restrict__ ln_b, unsigned short* __restrict__ proc2)
{
  const int f = blockIdx.y;
  const int nb = blockIdx.x;
  const int n0 = nb * 64;
  const int tid = threadIdx.x;
  const int wv = tid >> 6, l = tid & 63;
  __shared__ __align__(16) unsigned short As[64*136];
  __shared__ float xs[64];
  __shared__ float vbuf[64*129];
  __shared__ float red[64][4][2];
  __shared__ float mr[64][2];
  if (tid < 64) xs[tid] = x[(size_t)(n0+tid)*9 + f];
  __syncthreads();
  { int i = tid & 127;
    float w1 = fc1_w[f*128 + i], b1 = fc1_b[f*128 + i];
    for (int it = 0; it < 32; it++) {
      int tk = (tid >> 7) + it*2;
      As[tk*136 + i] = f2bu(eluf(xs[tk]*w1 + b1));
    }
  }
  __syncthreads();
  const unsigned short* Wp = pk + PK_VSN + (size_t)f*32768;
  f32x4 acc[4][4];
  #pragma unroll
  for (int rt = 0; rt < 4; rt++)
    #pragma unroll
    for (int ci = 0; ci < 4; ci++) acc[rt][ci] = (f32x4)(0.f);
  #pragma unroll
  for (int kc = 0; kc < 4; kc++) {
    short8 af[4];
    #pragma unroll
    for (int rt = 0; rt < 4; rt++) {
      int row = rt*16 + (l & 15), g = kc*4 + (l >> 4);
      af[rt] = *(const short8*)&As[row*136 + g*8];
    }
    short8 bf[4];
    #pragma unroll
    for (int ci = 0; ci < 4; ci++) {
      int ct = (ci < 2) ? (wv*2 + ci) : (8 + wv*2 + (ci-2));
      bf[ci] = *(const short8*)&Wp[(((size_t)ct*4 + kc)*64 + l)*8];
    }
    #pragma unroll
    for (int rt = 0; rt < 4; rt++)
      #pragma unroll
      for (int ci = 0; ci < 4; ci++)
        acc[rt][ci] = __builtin_amdgcn_mfma_f32_16x16x32_bf16(af[rt], bf[ci], acc[rt][ci], 0, 0, 0);
  }
  __syncthreads();
  #pragma unroll
  for (int ci = 0; ci < 2; ci++) {
    int ch = wv*32 + ci*16 + (l & 15);
    float fb = fc2_b[f*128 + ch], gb = gate_b[f*128 + ch];
    float sw = skip_w[f*128 + ch], sb = skip_b[f*128 + ch];
    #pragma unroll
    for (int rt = 0; rt < 4; rt++)
      #pragma unroll
      for (int r = 0; r < 4; r++) {
        int row = rt*16 + (l >> 4)*4 + r;
        float hv = acc[rt][ci][r] + fb;
        float gv = sigm(acc[rt][ci+2][r] + gb);
        float sv = xs[row]*sw + sb;
        vbuf[row*129 + ch] = sv + hv*gv;
      }
  }
  __syncthreads();
  { int tk = tid >> 2, q = tid & 3;
    float s1 = 0.f, s2 = 0.f;
    #pragma unroll
    for (int i = 0; i < 32; i++) { float z = vbuf[tk*129 + q*32 + i]; s1 += z; s2 += z*z; }
    red[tk][q][0] = s1; red[tk][q][1] = s2;
  }
  __syncthreads();
  if ((tid & 3) == 0) {
    int tk = tid >> 2;
    float a = 0.f, b2 = 0.f;
    for (int p = 0; p < 4; p++) { a += red[tk][p][0]; b2 += red[tk][p][1]; }
    float mean = a * 0.0078125f;
    float var = b2 * 0.0078125f - mean*mean;
    mr[tk][0] = mean; mr[tk][1] = rsqrtf(fmaxf(var, 0.f) + 1e-5f);
  }
  __syncthreads();
  { int i = tid & 127;
    float lg = ln_g[f*128 + i], lb = ln_b[f*128 + i];
    size_t base = ((size_t)nb*9 + f)*8192;
    for (int it = 0; it < 32; it++) {
      int tk = (tid >> 7) + it*2;
      float z = (vbuf[tk*129 + i] - mr[tk][0]) * mr[tk][1] * lg + lb;
      proc2[base + tk*128 + i] = f2bu(z);
    }
  }
}

// ---------------- grand-selection GRN (MFMA, fully fused) -> sel bf16 ------
__global__ __launch_bounds__(256) void k_gc_mfma(
    const unsigned short* __restrict__ proc2, const unsigned short* __restrict__ pk,
    const float* __restrict__ fc1_b, const float* __restrict__ fc2_b,
    const float* __restrict__ gate_b, const float* __restrict__ skip_b,
    const float* __restrict__ ln_g, const float* __restrict__ ln_b,
    unsigned short* __restrict__ selb)
{
  const int nb = blockIdx.x;
  const int n0 = nb * 64;
  const int tid = threadIdx.x;
  const int wv = tid >> 6, l = tid & 63;
  __shared__ __align__(16) unsigned short As[64*136];
  __shared__ __align__(16) unsigned short A2s[64*136];
  __shared__ float vbuf[64*129];
  __shared__ float red[64][4][2];
  __shared__ float mr[64][2];
  const unsigned short* W1 = pk + PK_GC1;
  f32x4 acc1[4][4];
  #pragma unroll
  for (int rt = 0; rt < 4; rt++)
    #pragma unroll
    for (int ci = 0; ci < 4; ci++) acc1[rt][ci] = (f32x4)(0.f);
  for (int c = 0; c < 9; c++) {
    size_t cbase = ((size_t)nb*9 + c)*8192;
    #pragma unroll
    for (int i = 0; i < 4; i++) {
      int gi = i*256 + tid;
      int row = gi >> 4, g = gi & 15;
      uint4 v = *(const uint4*)(proc2 + cbase + row*128 + g*8);
      *(uint4*)&As[row*136 + g*8] = v;
    }
    __syncthreads();
    #pragma unroll
    for (int kc = 0; kc < 4; kc++) {
      int kk = c*4 + kc;
      short8 af[4];
      #pragma unroll
      for (int rt = 0; rt < 4; rt++) {
        int row = rt*16 + (l & 15), g = kc*4 + (l >> 4);
        af[rt] = *(const short8*)&As[row*136 + g*8];
      }
      short8 bf[4];
      #pragma unroll
      for (int ci = 0; ci < 4; ci++) {
        int ct = (ci < 2) ? (wv*2 + ci) : (8 + wv*2 + (ci-2));
        bf[ci] = *(const short8*)&W1[(((size_t)ct*36 + kk)*64 + l)*8];
      }
      #pragma unroll
      for (int rt = 0; rt < 4; rt++)
        #pragma unroll
        for (int ci = 0; ci < 4; ci++)
          acc1[rt][ci] = __builtin_amdgcn_mfma_f32_16x16x32_bf16(af[rt], bf[ci], acc1[rt][ci], 0, 0, 0);
    }
    __syncthreads();
  }
  #pragma unroll
  for (int ci = 0; ci < 2; ci++) {
    int ch = wv*32 + ci*16 + (l & 15);
    float fb = fc1_b[ch];
    #pragma unroll
    for (int rt = 0; rt < 4; rt++)
      #pragma unroll
      for (int r = 0; r < 4; r++) {
        int row = rt*16 + (l >> 4)*4 + r;
        A2s[row*136 + ch] = f2bu(eluf(acc1[rt][ci][r] + fb));
      }
  }
  __syncthreads();
  const unsigned short* W2 = pk + PK_GC2;
  f32x4 acc2[4][4];
  #pragma unroll
  for (int rt = 0; rt < 4; rt++)
    #pragma unroll
    for (int ci = 0; ci < 4; ci++) acc2[rt][ci] = (f32x4)(0.f);
  #pragma unroll
  for (int kc = 0; kc < 4; kc++) {
    short8 af[4];
    #pragma unroll
    for (int rt = 0; rt < 4; rt++) {
      int row = rt*16 + (l & 15), g = kc*4 + (l >> 4);
      af[rt] = *(const short8*)&A2s[row*136 + g*8];
    }
    short8 bf[4];
    #pragma unroll
    for (int ci = 0; ci < 4; ci++) {
      int ct = (ci < 2) ? (wv*2 + ci) : (8 + wv*2 + (ci-2));
      bf[ci] = *(const short8*)&W2[(((size_t)ct*4 + kc)*64 + l)*8];
    }
    #pragma unroll
    for (int rt = 0; rt < 4; rt++)
      #pragma unroll
      for (int ci = 0; ci < 4; ci++)
        acc2[rt][ci] = __builtin_amdgcn_mfma_f32_16x16x32_bf16(af[rt], bf[ci], acc2[rt][ci], 0, 0, 0);
  }
  __syncthreads();
  #pragma unroll
  for (int ci = 0; ci < 2; ci++) {
    int ch = wv*32 + ci*16 + (l & 15);
    float f2 = fc2_b[ch], gb = gate_b[ch], sb = skip_b[ch];
    #pragma unroll
    for (int rt = 0; rt < 4; rt++)
      #pragma unroll
      for (int r = 0; r < 4; r++) {
        int row = rt*16 + (l >> 4)*4 + r;
        float hv = acc2[rt][ci][r] + f2;
        float gv = sigm(acc2[rt][ci+2][r] + gb);
        float sv = acc1[rt][ci+2][r] + sb;
        vbuf[row*129 + ch] = sv + hv*gv;
      }
  }
  __syncthreads();
  { int tk = tid >> 2, q = tid & 3;
    float s1 = 0.f, s2 = 0.f;
    #pragma unroll
    for (int i = 0; i < 32; i++) { float z = vbuf[tk*129 + q*32 + i]; s1 += z; s2 += z*z; }
    red[tk][q][0] = s1; red[tk][q][1] = s2;
  }
  __syncthreads();
  if ((tid & 3) == 0) {
    int tk = tid >> 2;
    float a = 0.f, b2 = 0.f;
    for (int p = 0; p < 4; p++) { a += red[tk][p][0]; b2 += red[tk][p][1]; }
    float mean = a * 0.0078125f;
    float var = b2 * 0.0078125f - mean*mean;
    mr[tk][0] = mean; mr[tk][1] = rsqrtf(fmaxf(var, 0.f) + 1e-5f);
  }
  __syncthreads();
  { int i = tid & 127;
    float lg = ln_g[i], lb = ln_b[i];
    for (int it = 0; it < 32; it++) {
      int tk = (tid >> 7) + it*2;
      float z = (vbuf[tk*129 + i] - mr[tk][0]) * mr[tk][1] * lg + lb;
      selb[(size_t)(n0+tk)*128 + i] = f2bu(z);
    }
  }
}

// ---------------- generic bf16 MFMA GEMM, out fp32 or f16 ------------------
__global__ __launch_bounds__(256) void k_mm(
    const unsigned short* __restrict__ A, const unsigned short* __restrict__ Wp,
    const float* __restrict__ b0, const float* __restrict__ b1,
    void* __restrict__ out, int out_ld, int outmode)
{
  const int r0 = blockIdx.x * 64;
  const int cb = blockIdx.y * 128;
  const int tid = threadIdx.x;
  const int wv = tid >> 6, l = tid & 63;
  __shared__ __align__(16) unsigned short As[64*136];
  #pragma unroll
  for (int i = 0; i < 4; i++) {
    int gi = i*256 + tid;
    int row = gi >> 4, g = gi & 15;
    uint4 v = *(const uint4*)(A + (size_t)(r0+row)*128 + g*8);
    *(uint4*)&As[row*136 + g*8] = v;
  }
  __syncthreads();
  f32x4 acc[4][2];
  #pragma unroll
  for (int rt = 0; rt < 4; rt++)
    #pragma unroll
    for (int ci = 0; ci < 2; ci++) acc[rt][ci] = (f32x4)(0.f);
  #pragma unroll
  for (int kc = 0; kc < 4; kc++) {
    short8 af[4];
    #pragma unroll
    for (int rt = 0; rt < 4; rt++) {
      int row = rt*16 + (l & 15), g = kc*4 + (l >> 4);
      af[rt] = *(const short8*)&As[row*136 + g*8];
    }
    short8 bf[2];
    #pragma unroll
    for (int ci = 0; ci < 2; ci++) {
      int ct = (cb >> 4) + wv*2 + ci;
      bf[ci] = *(const short8*)&Wp[(((size_t)ct*4 + kc)*64 + l)*8];
    }
    #pragma unroll
    for (int rt = 0; rt < 4; rt++)
      #pragma unroll
      for (int ci = 0; ci < 2; ci++)
        acc[rt][ci] = __builtin_amdgcn_mfma_f32_16x16x32_bf16(af[rt], bf[ci], acc[rt][ci], 0, 0, 0);
  }
  #pragma unroll
  for (int ci = 0; ci < 2; ci++) {
    int cl = cb + wv*32 + ci*16 + (l & 15);
    float bias = b0[cl] + (b1 ? b1[cl] : 0.f);
    #pragma unroll
    for (int rt = 0; rt < 4; rt++)
      #pragma unroll
      for (int r = 0; r < 4; r++) {
        int row = r0 + rt*16 + (l >> 4)*4 + r;
        float v = acc[rt][ci][r] + bias;
        if (outmode == 0) ((float*)out)[(size_t)row*out_ld + cl] = v;
        else ((unsigned short*)out)[(size_t)row*out_ld + cl] = f2h(v);
      }
  }
}

// ---------------- single-layer LSTM scan, fdot2 f16 ------------------------
// 256 threads, one block per batch element. Thread tid holds whh rows tid and
// tid+256 as packed-f16 pairs (128 uints -> VGPR-resident: the 256-thread
// shape gets a 176-VGPR budget from the allocator [r3-proven]; the 768-thread
// fused variant was pinned to 84 VGPR and spilled 101 MB/step [r6-r9]).
// pre is f16 with both biases folded in (k_mm outmode=1). Loads issued at
// step-top, consumed after the LDS-fed fdot2 matvec (~256 cyc of cover).
__global__ __launch_bounds__(256, 1) void k_lscan(
    const unsigned short* __restrict__ pre,   // f16 [B][T][512] (tstr=512) or [B][512] (tstr=0)
    const float* __restrict__ whh,
    const float* __restrict__ h0i, const float* __restrict__ c0i,
    int T, int tstr,
    unsigned short* __restrict__ ys,          // bf16 [B][T][128]
    float* __restrict__ hT, float* __restrict__ cT,
    unsigned short* __restrict__ hTb)         // bf16 [B][128]
{
  const int b = blockIdx.x, tid = threadIdx.x;
  unsigned int w0[64], w1[64];
  {
    const float* p0 = whh + (size_t)tid*128;
    const float* p1 = whh + (size_t)(tid+256)*128;
    #pragma unroll
    for (int k = 0; k < 64; k++) {
      w0[k] = pkh(p0[2*k], p0[2*k+1]);
      w1[k] = pkh(p1[2*k], p1[2*k+1]);
    }
  }
  __shared__ __align__(16) unsigned short hs[128];
  __shared__ float fg[256];
  float c = 0.f;
  if (tid < 128) {
    float h = h0i ? h0i[(size_t)b*128 + tid] : 0.f;
    c = c0i ? c0i[(size_t)b*128 + tid] : 0.f;
    hs[tid] = f2h(h);
  }
  __syncthreads();
  const unsigned short* preb = pre + (size_t)b * (tstr ? (size_t)T*tstr : 512);
  for (int t = 0; t < T; t++) {
    const unsigned short* pt = preb + (size_t)t*tstr;
    unsigned short p0 = pt[tid], p1 = pt[256 + tid];
    float a0[4] = {0.f,0.f,0.f,0.f}, a1[4] = {0.f,0.f,0.f,0.f};
    #pragma unroll
    for (int k4 = 0; k4 < 16; k4++) {
      uint4 hh = *(const uint4*)&hs[k4*8];
      a0[0] = fd2(w0[4*k4+0], hh.x, a0[0]);
      a0[1] = fd2(w0[4*k4+1], hh.y, a0[1]);
      a0[2] = fd2(w0[4*k4+2], hh.z, a0[2]);
      a0[3] = fd2(w0[4*k4+3], hh.w, a0[3]);
      a1[0] = fd2(w1[4*k4+0], hh.x, a1[0]);
      a1[1] = fd2(w1[4*k4+1], hh.y, a1[1]);
      a1[2] = fd2(w1[4*k4+2], hh.z, a1[2]);
      a1[3] = fd2(w1[4*k4+3], hh.w, a1[3]);
    }
    float g0 = h2f(p0) + (a0[0]+a0[1]) + (a0[2]+a0[3]);
    float g1 = h2f(p1) + (a1[0]+a1[1]) + (a1[2]+a1[3]);
    if (tid >= 128) { fg[tid-128] = g0; fg[tid] = g1; }
    __syncthreads();
    if (tid < 128) {
      float iv = sigm(g0);
      float gv = tanhx(g1);
      float fv = sigm(fg[tid]);
      float ov = sigm(fg[128 + tid]);
      c = fv*c + iv*gv;
      float h = ov * tanhx(c);
      hs[tid] = f2h(h);
      ys[((size_t)b*T + t)*128 + tid] = f2bu(h);
      if (t == T-1) {
        hT[(size_t)b*128 + tid] = h;
        cT[(size_t)b*128 + tid] = c;
        hTb[(size_t)b*128 + tid] = f2bu(h);
      }
    }
    __syncthreads();
  }
}

// ---------------- cross attention: one block per (batch, head) -------------
__global__ __launch_bounds__(256) void k_attn(
    const float* __restrict__ Q, const float* __restrict__ K, const float* __restrict__ V,
    unsigned short* __restrict__ o)
{
  const int b = blockIdx.x, h = blockIdx.y, tid = threadIdx.x;
  __shared__ float Ks[168][33];
  __shared__ float Vs[168][32];
  __shared__ float Qs[24][32];
  __shared__ float Sc[24][169];
  __shared__ float red[24][8];
  __shared__ float rowm[24], rows[24];
  for (int e = tid; e < 168*32; e += 256) {
    int t = e >> 5, d = e & 31;
    Ks[t][d] = K[((size_t)b*168 + t)*128 + h*32 + d];
    Vs[t][d] = V[((size_t)b*168 + t)*128 + h*32 + d];
  }
  for (int e = tid; e < 24*32; e += 256) {
    int q = e >> 5, d = e & 31;
    Qs[q][d] = Q[((size_t)b*24 + q)*128 + h*32 + d];
  }
  __syncthreads();
  for (int e = tid; e < 24*168; e += 256) {
    int q = e / 168, t = e - q*168;
    float s = 0.f;
    #pragma unroll
    for (int d = 0; d < 32; d++) s += Qs[q][d]*Ks[t][d];
    Sc[q][t] = s * 0.17677669529663687f;
  }
  __syncthreads();
  int q = tid >> 3, l8 = tid & 7;
  if (q < 24) {
    float m = -1e30f;
    for (int t = l8; t < 168; t += 8) m = fmaxf(m, Sc[q][t]);
    red[q][l8] = m;
  }
  __syncthreads();
  if (q < 24 && l8 == 0) {
    float m = red[q][0];
    for (int p = 1; p < 8; p++) m = fmaxf(m, red[q][p]);
    rowm[q] = m;
  }
  __syncthreads();
  if (q < 24) {
    float s = 0.f;
    for (int t = l8; t < 168; t += 8) {
      float e2 = __expf(Sc[q][t] - rowm[q]);
      Sc[q][t] = e2; s += e2;
    }
    red[q][l8] = s;
  }
  __syncthreads();
  if (q < 24 && l8 == 0) {
    float s = 0.f;
    for (int p = 0; p < 8; p++) s += red[q][p];
    rows[q] = 1.f/s;
  }
  __syncthreads();
  for (int e = tid; e < 24*32; e += 256) {
    int qq = e >> 5, d = e & 31;
    float acc = 0.f;
    for (int t = 0; t < 168; t++) acc += Sc[qq][t]*Vs[t][d];
    o[((size_t)b*24 + qq)*128 + h*32 + d] = f2bu(acc * rows[qq]);
  }
}

// ---------------- post-attention GRN (identity skip), 32 tokens/block ------
__global__ __launch_bounds__(256) void k_pa_grn(
    const float* __restrict__ xin, const float* __restrict__ wt,
    const float* __restrict__ fc1_b, const float* __restrict__ fc2_b,
    const float* __restrict__ gate_b, const float* __restrict__ ln_g,
    const float* __restrict__ ln_b, float* __restrict__ out)
{
  const int n0 = blockIdx.x * 32;
  const int tid = threadIdx.x;
  __shared__ float xs[32][130];
  __shared__ float h1[32][130];
  __shared__ float red[32][8][2];
  __shared__ float mr[32][2];
  for (int t4 = tid; t4 < 1024; t4 += 256) {
    int r = t4 >> 5, c = (t4 & 31) << 2;
    float4 v = *(const float4*)(xin + (size_t)(n0 + r)*128 + c);
    xs[r][c] = v.x; xs[r][c+1] = v.y; xs[r][c+2] = v.z; xs[r][c+3] = v.w;
  }
  __syncthreads();
  const int oo = tid & 15, tt = tid >> 4;
  const float* fc1t = wt + OFF_PA_FC1T;
  {
    float af[2][8];
    #pragma unroll
    for (int j = 0; j < 2; j++)
      #pragma unroll
      for (int c = 0; c < 8; c++) af[j][c] = 0.f;
    for (int k = 0; k < 128; k++) {
      float4 wa = *(const float4*)(fc1t + k*128 + oo*4);
      float4 wb = *(const float4*)(fc1t + k*128 + 64 + oo*4);
      float wv[8] = {wa.x,wa.y,wa.z,wa.w,wb.x,wb.y,wb.z,wb.w};
      #pragma unroll
      for (int j = 0; j < 2; j++) {
        float a = xs[tt*2+j][k];
        #pragma unroll
        for (int c = 0; c < 8; c++) af[j][c] += a*wv[c];
      }
    }
    #pragma unroll
    for (int j = 0; j < 2; j++) {
      int tk = tt*2 + j;
      #pragma unroll
      for (int c = 0; c < 8; c++) {
        int col = (c < 4) ? (oo*4 + c) : (64 + oo*4 + (c-4));
        h1[tk][col] = eluf(af[j][c] + fc1_b[col]);
      }
    }
  }
  __syncthreads();
  const float* fc2t = wt + OFF_PA_FC2T;
  const float* gtt  = wt + OFF_PA_GATET;
  float ah[2][8], ag[2][8];
  #pragma unroll
  for (int j = 0; j < 2; j++)
    #pragma unroll
    for (int c = 0; c < 8; c++) { ah[j][c] = 0.f; ag[j][c] = 0.f; }
  for (int k = 0; k < 128; k++) {
    float4 wa = *(const float4*)(fc2t + k*128 + oo*4);
    float4 wb = *(const float4*)(fc2t + k*128 + 64 + oo*4);
    float4 wc = *(const float4*)(gtt + k*128 + oo*4);
    float4 wd = *(const float4*)(gtt + k*128 + 64 + oo*4);
    float whv[8] = {wa.x,wa.y,wa.z,wa.w,wb.x,wb.y,wb.z,wb.w};
    float wgv[8] = {wc.x,wc.y,wc.z,wc.w,wd.x,wd.y,wd.z,wd.w};
    #pragma unroll
    for (int j = 0; j < 2; j++) {
      float a = h1[tt*2+j][k];
      #pragma unroll
      for (int c = 0; c < 8; c++) { ah[j][c] += a*whv[c]; ag[j][c] += a*wgv[c]; }
    }
  }
  __syncthreads();
  #pragma unroll
  for (int j = 0; j < 2; j++) {
    int tk = tt*2 + j;
    #pragma unroll
    for (int c = 0; c < 8; c++) {
      int col = (c < 4) ? (oo*4 + c) : (64 + oo*4 + (c-4));
      float hv = ah[j][c] + fc2_b[col];
      float gv = sigm(ag[j][c] + gate_b[col]);
      xs[tk][col] = xs[tk][col] + hv*gv;
    }
  }
  __syncthreads();
  { int tk = tid >> 3, qq = tid & 7;
    float s1 = 0.f, s2 = 0.f;
    #pragma unroll
    for (int i = 0; i < 16; i++) { float z = xs[tk][qq*16+i]; s1 += z; s2 += z*z; }
    red[tk][qq][0] = s1; red[tk][qq][1] = s2;
  }
  __syncthreads();
  if ((tid & 7) == 0) {
    int tk = tid >> 3;
    float a = 0.f, b2 = 0.f;
    for (int p = 0; p < 8; p++) { a += red[tk][p][0]; b2 += red[tk][p][1]; }
    float mean = a * 0.0078125f;
    float var = b2 * 0.0078125f - mean*mean;
    mr[tk][0] = mean; mr[tk][1] = rsqrtf(fmaxf(var, 0.f) + 1e-5f);
  }
  __syncthreads();
  for (int e = tid; e < 32*128; e += 256) {
    int r = e >> 7, c = e & 127;
    out[(size_t)(n0+r)*128 + c] = (xs[r][c] - mr[r][0]) * mr[r][1] * ln_g[c] + ln_b[c];
  }
}

// ---------------- final projection 128 -> 6 --------------------------------
__global__ __launch_bounds__(256) void k_final(
    const float* __restrict__ a, const float* __restrict__ fo_w,
    const float* __restrict__ fo_b, float* __restrict__ out)
{
  int idx = blockIdx.x*256 + threadIdx.x;
  if (idx >= NDTOK*6) return;
  int n = idx / 6, j = idx - n*6;
  const float* ar = a + (size_t)n*128;
  const float* w = fo_w + j*128;
  float s = fo_b[j];
  #pragma unroll 4
  for (int d = 0; d < 128; d++) s += ar[d]*w[d];
  out[idx] = s;
}

extern "C" void kernel_launch(void* const* d_in, const int* in_sizes, int n_in,
                              void* d_out, int out_size, void* d_ws, size_t ws_size,
                              hipStream_t stream) {
  (void)in_sizes; (void)n_in; (void)out_size; (void)ws_size;
  const float* x      = (const float*)d_in[0];
  const float* vfc1w  = (const float*)d_in[1];
  const float* vfc1b  = (const float*)d_in[2];
  const float* vfc2w  = (const float*)d_in[3];
  const float* vfc2b  = (const float*)d_in[4];
  const float* vgw    = (const float*)d_in[5];
  const float* vgb    = (const float*)d_in[6];
  const float* vskw   = (const float*)d_in[7];
  const float* vskb   = (const float*)d_in[8];
  const float* vlng   = (const float*)d_in[9];
  const float* vlnb   = (const float*)d_in[10];
  const float* gfc1w  = (const float*)d_in[11];
  const float* gfc1b  = (const float*)d_in[12];
  const float* gfc2w  = (const float*)d_in[13];
  const float* gfc2b  = (const float*)d_in[14];
  const float* ggw    = (const float*)d_in[15];
  const float* ggb    = (const float*)d_in[16];
  const float* gskw   = (const float*)d_in[17];
  const float* gskb   = (const float*)d_in[18];
  const float* glng   = (const float*)d_in[19];
  const float* glnb   = (const float*)d_in[20];
  const float* encwih = (const float*)d_in[21];
  const float* encwhh = (const float*)d_in[22];
  const float* encbih = (const float*)d_in[23];
  const float* encbhh = (const float*)d_in[24];
  const float* decwih = (const float*)d_in[25];
  const float* decwhh = (const float*)d_in[26];
  const float* decbih = (const float*)d_in[27];
  const float* decbhh = (const float*)d_in[28];
  const float* ainw   = (const float*)d_in[29];
  const float* ainb   = (const float*)d_in[30];
  const float* aoutw  = (const float*)d_in[31];
  const float* aoutb  = (const float*)d_in[32];
  const float* pfc1w  = (const float*)d_in[33];
  const float* pfc1b  = (const float*)d_in[34];
  const float* pfc2w  = (const float*)d_in[35];
  const float* pfc2b  = (const float*)d_in[36];
  const float* pgw    = (const float*)d_in[37];
  const float* pgb    = (const float*)d_in[38];
  const float* plng   = (const float*)d_in[39];
  const float* plnb   = (const float*)d_in[40];
  const float* fow    = (const float*)d_in[41];
  const float* fob    = (const float*)d_in[42];

  float* ws = (float*)d_ws;
  // ---- workspace (float offsets). Sizes: bf16/f16 [43008,128]=2,752,512 fl;
  // f16 [43008,512]=11,010,048 fl; proc2=24,772,608 fl; pk=475,136 fl.
  float* wtp = ws;                                        // [0, 49,152)
  unsigned short* pk = (unsigned short*)(ws + 50000);     // [50,000, 525,136)
  unsigned short* proc2 = (unsigned short*)(ws + 530000); // [530,000, 25,302,608)
  unsigned short* pre = (unsigned short*)(ws + 530000);   // f16 [43008][512] alias (after proc2 dead) -> 11,540,048
  float* Kb   = ws + 530000;                              // f32 [43008,128] (after pre dead) -> 6,035,024
  float* Vb   = ws + 6100000;                             // -> 11,605,024
  unsigned short* pre2 = (unsigned short*)(ws + 11700000);// f16 [6144,512] -> 13,272,864
  float* Qb   = ws + 13300000;                            // -> 14,086,432
  unsigned short* attb = (unsigned short*)(ws + 14100000);// -> 14,296,608
  float* ato  = ws + 14300000;                            // -> 15,086,432
  float* pao  = ws + 15100000;                            // -> 15,886,432
  unsigned short* pd0 = (unsigned short*)(ws + 15900000); // f16 [256,512] -> 15,965,536
  unsigned short* selb  = (unsigned short*)(ws + 25350000); // bf16 [43008,128] -> 28,102,512
  unsigned short* encob = (unsigned short*)(ws + 28150000); // bf16 [43008,128] -> 30,902,512
  unsigned short* ys0b  = (unsigned short*)(ws + 30950000); // bf16 [43008,128] -> 33,702,512
  unsigned short* dys0b = (unsigned short*)(ws + 33750000); // bf16 [6144,128] -> 33,946,608
  unsigned short* dout2b = (unsigned short*)(ws + 33950000);// bf16 [6144,128] -> 34,146,608
  float* hT0  = ws + 34150000;  float* cT0 = ws + 34190000;
  float* hT1  = ws + 34230000;  float* cT1 = ws + 34270000;
  unsigned short* hT1b = (unsigned short*)(ws + 34310000);  // bf16 [256,128]
  float* dscr = ws + 34350000;  // dummy hT/cT/hTb for scans that don't need them

  // 1. PA-GRN fp32 transposes
  k_transpose3<<<dim3(192), dim3(256), 0, stream>>>(wtp, pfc1w, pfc2w, pgw);
  // 2. pack bf16 MFMA fragments
  k_pack<<<dim3(128, 9), dim3(256), 0, stream>>>(vfc2w, vgw, pk + PK_VSN, 128, 256, 128, 16384, 16384, 32768);
  k_pack<<<dim3(1152), dim3(256), 0, stream>>>(gfc1w, gskw, pk + PK_GC1, 1152, 256, 128, 0, 0, 0);
  k_pack<<<dim3(128), dim3(256), 0, stream>>>(gfc2w, ggw, pk + PK_GC2, 128, 256, 128, 0, 0, 0);
  k_pack<<<dim3(256), dim3(256), 0, stream>>>(encwih, encwih, pk + PK_ENC0, 128, 512, 512, 0, 0, 0);
  k_pack<<<dim3(256), dim3(256), 0, stream>>>(encwih + 65536, encwih, pk + PK_ENC1, 128, 512, 512, 0, 0, 0);
  k_pack<<<dim3(256), dim3(256), 0, stream>>>(decwih, decwih, pk + PK_DEC0, 128, 512, 512, 0, 0, 0);
  k_pack<<<dim3(256), dim3(256), 0, stream>>>(decwih + 65536, decwih, pk + PK_DEC1, 128, 512, 512, 0, 0, 0);
  k_pack<<<dim3(192), dim3(256), 0, stream>>>(ainw, ainw, pk + PK_AIN, 128, 384, 384, 0, 0, 0);
  k_pack<<<dim3(64), dim3(256), 0, stream>>>(aoutw, aoutw, pk + PK_AOUT, 128, 128, 128, 0, 0, 0);
  // 3. VSN per-feature GRNs (MFMA)
  k_vsn_mfma<<<dim3(672, 9), dim3(256), 0, stream>>>(x, vfc1w, vfc1b, pk,
      vfc2b, vgb, vskw, vskb, vlng, vlnb, proc2);
  // 4. grand-selection GRN (MFMA, fused)
  k_gc_mfma<<<dim3(672), dim3(256), 0, stream>>>(proc2, pk, gfc1b, gfc2b, ggb,
      gskb, glng, glnb, selb);
  // 5. encoder layer 0: input projection (f16, biases folded) + scan
  k_mm<<<dim3(672, 4), dim3(256), 0, stream>>>(selb, pk + PK_ENC0, encbih, encbhh, pre, 512, 1);
  k_lscan<<<dim3(256), dim3(256), 0, stream>>>(pre, encwhh, nullptr, nullptr,
      TSE, 512, ys0b, hT0, cT0, (unsigned short*)dscr);
  // 6. encoder layer 1
  k_mm<<<dim3(672, 4), dim3(256), 0, stream>>>(ys0b, pk + PK_ENC1, encbih + 512, encbhh + 512, pre, 512, 1);
  k_lscan<<<dim3(256), dim3(256), 0, stream>>>(pre, encwhh + 65536, nullptr, nullptr,
      TSE, 512, encob, hT1, cT1, hT1b);
  // 7. decoder layer 0 (constant input hT1)
  k_mm<<<dim3(4, 4), dim3(256), 0, stream>>>(hT1b, pk + PK_DEC0, decbih, decbhh, pd0, 512, 1);
  k_lscan<<<dim3(256), dim3(256), 0, stream>>>(pd0, decwhh, hT0, cT0,
      TSD, 0, dys0b, dscr + 40000, dscr + 80000, (unsigned short*)dscr);
  // 8. decoder layer 1
  k_mm<<<dim3(96, 4), dim3(256), 0, stream>>>(dys0b, pk + PK_DEC1, decbih + 512, decbhh + 512, pre2, 512, 1);
  k_lscan<<<dim3(256), dim3(256), 0, stream>>>(pre2, decwhh + 65536, hT1, cT1,
      TSD, 512, dout2b, dscr + 120000, dscr + 160000, (unsigned short*)dscr);
  // 9. attention projections
  k_mm<<<dim3(96, 1), dim3(256), 0, stream>>>(dout2b, pk + PK_AIN, ainb, nullptr, Qb, 128, 0);
  k_mm<<<dim3(672, 1), dim3(256), 0, stream>>>(encob, pk + PK_AIN + 16384, ainb + 128, nullptr, Kb, 128, 0);
  k_mm<<<dim3(672, 1), dim3(256), 0, stream>>>(encob, pk + PK_AIN + 32768, ainb + 256, nullptr, Vb, 128, 0);
  // 10. attention core
  k_attn<<<dim3(256, 4), dim3(256), 0, stream>>>(Qb, Kb, Vb, attb);
  // 11. attention output projection
  k_mm<<<dim3(96, 1), dim3(256), 0, stream>>>(attb, pk + PK_AOUT, aoutb, nullptr, ato, 128, 0);
  // 12. post-attention GRN
  k_pa_grn<<<dim3(192), dim3(256), 0, stream>>>(ato, wtp, pfc1b, pfc2b, pgb,
      plng, plnb, pao);
  // 13. final projection
  k_final<<<dim3(144), dim3(256), 0, stream>>>(pao, fow, fob, (float*)d_out);
}

// Round 11
// 738.141 us; speedup vs baseline: 1.4073x; 1.0357x over previous
//
#include <hip/hip_runtime.h>
#include <hip/hip_bf16.h>

#define NBATCH 256
#define TSE 168
#define TSD 24
#define NTOK (NBATCH*TSE)   // 43008
#define NDTOK (NBATCH*TSD)  // 6144

// packed bf16 MFMA-B-fragment offsets (ushort units, region base pk)
#define PK_VSN    0         // 9 x [K=128, NC=256]  = 294912
#define PK_GC1    294912    // [K=1152, NC=256]     = 294912
#define PK_GC2    589824    // [K=128, NC=256]      = 32768
#define PK_ENC0   622592    // [128,512]            = 65536
#define PK_ENC1   688128    // [128,512]            = 65536
#define PK_DEC0   753664    // [128,512]            = 65536
#define PK_DEC1   819200    // [128,512]            = 65536
#define PK_AIN    884736    // [128,384]            = 49152
#define PK_AOUT   933888    // [128,128]            = 16384
#define PK_PAF1   950272    // [128,128]            = 16384
#define PK_PAF2G  966656    // [128,256]            = 32768
// pk total = 999,424 ushorts = 499,712 floats

typedef __attribute__((ext_vector_type(8))) short short8;
typedef __attribute__((ext_vector_type(4))) float f32x4;
typedef __attribute__((ext_vector_type(2))) __fp16 fp16x2;

__device__ __forceinline__ float sigm(float x){ return 1.f/(1.f + __expf(-x)); }
__device__ __forceinline__ float tanhx(float x){
  float cx = fminf(fmaxf(x, -15.f), 15.f);
  float e = __expf(2.f*cx);
  return (e-1.f)/(e+1.f);
}
__device__ __forceinline__ float eluf(float x){ return x > 0.f ? x : (__expf(x)-1.f); }
__device__ __forceinline__ unsigned short f2bu(float v){
  unsigned int u = __float_as_uint(v);
  u = (u + 0x7fffu + ((u>>16)&1u)) >> 16;
  return (unsigned short)u;
}
__device__ __forceinline__ unsigned int pkh(float a, float b){
  union { fp16x2 h; unsigned int u; } v;
  v.h = __builtin_amdgcn_cvt_pkrtz(a, b);
  return v.u;
}
__device__ __forceinline__ unsigned short f2h(float x){
  union { _Float16 h; unsigned short u; } v;
  v.h = (_Float16)x; return v.u;
}
__device__ __forceinline__ float h2f(unsigned short u){
  union { unsigned short u; _Float16 h; } v;
  v.u = u; return (float)v.h;
}
__device__ __forceinline__ float fd2(unsigned int a, unsigned int b, float c){
  union { unsigned int u; fp16x2 h; } ua, ub;
  ua.u = a; ub.u = b;
  return __builtin_amdgcn_fdot2(ua.h, ub.h, c, false);
}

// ---------------- pack weights into bf16 MFMA B-fragment order -------------
// dst layout: [ct][kc][lane(64)][j(8)], ct=n/16, kc=k/32, lane=(n%16)+16*((k%32)/8), j=k%8
__global__ __launch_bounds__(256) void k_pack(
    const float* __restrict__ s0, const float* __restrict__ s1,
    unsigned short* __restrict__ dst, int K, int NC, int nsplit,
    int s0bs, int s1bs, int dstbs)
{
  int id = blockIdx.x*256 + threadIdx.x;
  if (id >= K*NC) return;
  int by = blockIdx.y;
  int n = id / K, k = id - n*K;
  float v = (n < nsplit) ? s0[(size_t)by*s0bs + (size_t)n*K + k]
                         : s1[(size_t)by*s1bs + (size_t)(n-nsplit)*K + k];
  int ct = n >> 4, kc = k >> 5;
  int lane = (n & 15) | (((k >> 3) & 3) << 4);
  int j = k & 7;
  int KC = K >> 5;
  dst[(size_t)by*dstbs + (((size_t)ct*KC + kc)*64 + lane)*8 + j] = f2bu(v);
}

// ---------------- VSN per-feature GRN (MFMA) -> proc2 chunk-major bf16 -----
__global__ __launch_bounds__(256) void k_vsn_mfma(
    const float* __restrict__ x, const float* __restrict__ fc1_w, const float* __restrict__ fc1_b,
    const unsigned short* __restrict__ pk, const float* __restrict__ fc2_b,
    const float* __restrict__ gate_b, const float* __restrict__ skip_w,
    const float* __restrict__ skip_b, const float* __restrict__ ln_g,
    const float* __restrict__ ln_b, unsigned short* __restrict__ proc2)
{
  const int f = blockIdx.y;
  const int nb = blockIdx.x;
  const int n0 = nb * 64;
  const int tid = threadIdx.x;
  const int wv = tid >> 6, l = tid & 63;
  __shared__ __align__(16) unsigned short As[64*136];
  __shared__ float xs[64];
  __shared__ float vbuf[64*129];
  __shared__ float red[64][4][2];
  __shared__ float mr[64][2];
  if (tid < 64) xs[tid] = x[(size_t)(n0+tid)*9 + f];
  __syncthreads();
  { int i = tid & 127;
    float w1 = fc1_w[f*128 + i], b1 = fc1_b[f*128 + i];
    for (int it = 0; it < 32; it++) {
      int tk = (tid >> 7) + it*2;
      As[tk*136 + i] = f2bu(eluf(xs[tk]*w1 + b1));
    }
  }
  __syncthreads();
  const unsigned short* Wp = pk + PK_VSN + (size_t)f*32768;
  f32x4 acc[4][4];
  #pragma unroll
  for (int rt = 0; rt < 4; rt++)
    #pragma unroll
    for (int ci = 0; ci < 4; ci++) acc[rt][ci] = (f32x4)(0.f);
  #pragma unroll
  for (int kc = 0; kc < 4; kc++) {
    short8 af[4];
    #pragma unroll
    for (int rt = 0; rt < 4; rt++) {
      int row = rt*16 + (l & 15), g = kc*4 + (l >> 4);
      af[rt] = *(const short8*)&As[row*136 + g*8];
    }
    short8 bf[4];
    #pragma unroll
    for (int ci = 0; ci < 4; ci++) {
      int ct = (ci < 2) ? (wv*2 + ci) : (8 + wv*2 + (ci-2));
      bf[ci] = *(const short8*)&Wp[(((size_t)ct*4 + kc)*64 + l)*8];
    }
    #pragma unroll
    for (int rt = 0; rt < 4; rt++)
      #pragma unroll
      for (int ci = 0; ci < 4; ci++)
        acc[rt][ci] = __builtin_amdgcn_mfma_f32_16x16x32_bf16(af[rt], bf[ci], acc[rt][ci], 0, 0, 0);
  }
  __syncthreads();
  #pragma unroll
  for (int ci = 0; ci < 2; ci++) {
    int ch = wv*32 + ci*16 + (l & 15);
    float fb = fc2_b[f*128 + ch], gb = gate_b[f*128 + ch];
    float sw = skip_w[f*128 + ch], sb = skip_b[f*128 + ch];
    #pragma unroll
    for (int rt = 0; rt < 4; rt++)
      #pragma unroll
      for (int r = 0; r < 4; r++) {
        int row = rt*16 + (l >> 4)*4 + r;
        float hv = acc[rt][ci][r] + fb;
        float gv = sigm(acc[rt][ci+2][r] + gb);
        float sv = xs[row]*sw + sb;
        vbuf[row*129 + ch] = sv + hv*gv;
      }
  }
  __syncthreads();
  { int tk = tid >> 2, q = tid & 3;
    float s1 = 0.f, s2 = 0.f;
    #pragma unroll
    for (int i = 0; i < 32; i++) { float z = vbuf[tk*129 + q*32 + i]; s1 += z; s2 += z*z; }
    red[tk][q][0] = s1; red[tk][q][1] = s2;
  }
  __syncthreads();
  if ((tid & 3) == 0) {
    int tk = tid >> 2;
    float a = 0.f, b2 = 0.f;
    for (int p = 0; p < 4; p++) { a += red[tk][p][0]; b2 += red[tk][p][1]; }
    float mean = a * 0.0078125f;
    float var = b2 * 0.0078125f - mean*mean;
    mr[tk][0] = mean; mr[tk][1] = rsqrtf(fmaxf(var, 0.f) + 1e-5f);
  }
  __syncthreads();
  { int i = tid & 127;
    float lg = ln_g[f*128 + i], lb = ln_b[f*128 + i];
    size_t base = ((size_t)nb*9 + f)*8192;
    for (int it = 0; it < 32; it++) {
      int tk = (tid >> 7) + it*2;
      float z = (vbuf[tk*129 + i] - mr[tk][0]) * mr[tk][1] * lg + lb;
      proc2[base + tk*128 + i] = f2bu(z);
    }
  }
}

// ---------------- grand-selection GRN (MFMA, fully fused) -> sel bf16 ------
__global__ __launch_bounds__(256) void k_gc_mfma(
    const unsigned short* __restrict__ proc2, const unsigned short* __restrict__ pk,
    const float* __restrict__ fc1_b, const float* __restrict__ fc2_b,
    const float* __restrict__ gate_b, const float* __restrict__ skip_b,
    const float* __restrict__ ln_g, const float* __restrict__ ln_b,
    unsigned short* __restrict__ selb)
{
  const int nb = blockIdx.x;
  const int n0 = nb * 64;
  const int tid = threadIdx.x;
  const int wv = tid >> 6, l = tid & 63;
  __shared__ __align__(16) unsigned short As[64*136];
  __shared__ __align__(16) unsigned short A2s[64*136];
  __shared__ float vbuf[64*129];
  __shared__ float red[64][4][2];
  __shared__ float mr[64][2];
  const unsigned short* W1 = pk + PK_GC1;
  f32x4 acc1[4][4];
  #pragma unroll
  for (int rt = 0; rt < 4; rt++)
    #pragma unroll
    for (int ci = 0; ci < 4; ci++) acc1[rt][ci] = (f32x4)(0.f);
  for (int c = 0; c < 9; c++) {
    size_t cbase = ((size_t)nb*9 + c)*8192;
    #pragma unroll
    for (int i = 0; i < 4; i++) {
      int gi = i*256 + tid;
      int row = gi >> 4, g = gi & 15;
      uint4 v = *(const uint4*)(proc2 + cbase + row*128 + g*8);
      *(uint4*)&As[row*136 + g*8] = v;
    }
    __syncthreads();
    #pragma unroll
    for (int kc = 0; kc < 4; kc++) {
      int kk = c*4 + kc;
      short8 af[4];
      #pragma unroll
      for (int rt = 0; rt < 4; rt++) {
        int row = rt*16 + (l & 15), g = kc*4 + (l >> 4);
        af[rt] = *(const short8*)&As[row*136 + g*8];
      }
      short8 bf[4];
      #pragma unroll
      for (int ci = 0; ci < 4; ci++) {
        int ct = (ci < 2) ? (wv*2 + ci) : (8 + wv*2 + (ci-2));
        bf[ci] = *(const short8*)&W1[(((size_t)ct*36 + kk)*64 + l)*8];
      }
      #pragma unroll
      for (int rt = 0; rt < 4; rt++)
        #pragma unroll
        for (int ci = 0; ci < 4; ci++)
          acc1[rt][ci] = __builtin_amdgcn_mfma_f32_16x16x32_bf16(af[rt], bf[ci], acc1[rt][ci], 0, 0, 0);
    }
    __syncthreads();
  }
  #pragma unroll
  for (int ci = 0; ci < 2; ci++) {
    int ch = wv*32 + ci*16 + (l & 15);
    float fb = fc1_b[ch];
    #pragma unroll
    for (int rt = 0; rt < 4; rt++)
      #pragma unroll
      for (int r = 0; r < 4; r++) {
        int row = rt*16 + (l >> 4)*4 + r;
        A2s[row*136 + ch] = f2bu(eluf(acc1[rt][ci][r] + fb));
      }
  }
  __syncthreads();
  const unsigned short* W2 = pk + PK_GC2;
  f32x4 acc2[4][4];
  #pragma unroll
  for (int rt = 0; rt < 4; rt++)
    #pragma unroll
    for (int ci = 0; ci < 4; ci++) acc2[rt][ci] = (f32x4)(0.f);
  #pragma unroll
  for (int kc = 0; kc < 4; kc++) {
    short8 af[4];
    #pragma unroll
    for (int rt = 0; rt < 4; rt++) {
      int row = rt*16 + (l & 15), g = kc*4 + (l >> 4);
      af[rt] = *(const short8*)&A2s[row*136 + g*8];
    }
    short8 bf[4];
    #pragma unroll
    for (int ci = 0; ci < 4; ci++) {
      int ct = (ci < 2) ? (wv*2 + ci) : (8 + wv*2 + (ci-2));
      bf[ci] = *(const short8*)&W2[(((size_t)ct*4 + kc)*64 + l)*8];
    }
    #pragma unroll
    for (int rt = 0; rt < 4; rt++)
      #pragma unroll
      for (int ci = 0; ci < 4; ci++)
        acc2[rt][ci] = __builtin_amdgcn_mfma_f32_16x16x32_bf16(af[rt], bf[ci], acc2[rt][ci], 0, 0, 0);
  }
  __syncthreads();
  #pragma unroll
  for (int ci = 0; ci < 2; ci++) {
    int ch = wv*32 + ci*16 + (l & 15);
    float f2 = fc2_b[ch], gb = gate_b[ch], sb = skip_b[ch];
    #pragma unroll
    for (int rt = 0; rt < 4; rt++)
      #pragma unroll
      for (int r = 0; r < 4; r++) {
        int row = rt*16 + (l >> 4)*4 + r;
        float hv = acc2[rt][ci][r] + f2;
        float gv = sigm(acc2[rt][ci+2][r] + gb);
        float sv = acc1[rt][ci+2][r] + sb;
        vbuf[row*129 + ch] = sv + hv*gv;
      }
  }
  __syncthreads();
  { int tk = tid >> 2, q = tid & 3;
    float s1 = 0.f, s2 = 0.f;
    #pragma unroll
    for (int i = 0; i < 32; i++) { float z = vbuf[tk*129 + q*32 + i]; s1 += z; s2 += z*z; }
    red[tk][q][0] = s1; red[tk][q][1] = s2;
  }
  __syncthreads();
  if ((tid & 3) == 0) {
    int tk = tid >> 2;
    float a = 0.f, b2 = 0.f;
    for (int p = 0; p < 4; p++) { a += red[tk][p][0]; b2 += red[tk][p][1]; }
    float mean = a * 0.0078125f;
    float var = b2 * 0.0078125f - mean*mean;
    mr[tk][0] = mean; mr[tk][1] = rsqrtf(fmaxf(var, 0.f) + 1e-5f);
  }
  __syncthreads();
  { int i = tid & 127;
    float lg = ln_g[i], lb = ln_b[i];
    for (int it = 0; it < 32; it++) {
      int tk = (tid >> 7) + it*2;
      float z = (vbuf[tk*129 + i] - mr[tk][0]) * mr[tk][1] * lg + lb;
      selb[(size_t)(n0+tk)*128 + i] = f2bu(z);
    }
  }
}

// ---------------- generic bf16 MFMA GEMM, out fp32 or f16 ------------------
__global__ __launch_bounds__(256) void k_mm(
    const unsigned short* __restrict__ A, const unsigned short* __restrict__ Wp,
    const float* __restrict__ b0, const float* __restrict__ b1,
    void* __restrict__ out, int out_ld, int outmode)
{
  const int r0 = blockIdx.x * 64;
  const int cb = blockIdx.y * 128;
  const int tid = threadIdx.x;
  const int wv = tid >> 6, l = tid & 63;
  __shared__ __align__(16) unsigned short As[64*136];
  #pragma unroll
  for (int i = 0; i < 4; i++) {
    int gi = i*256 + tid;
    int row = gi >> 4, g = gi & 15;
    uint4 v = *(const uint4*)(A + (size_t)(r0+row)*128 + g*8);
    *(uint4*)&As[row*136 + g*8] = v;
  }
  __syncthreads();
  f32x4 acc[4][2];
  #pragma unroll
  for (int rt = 0; rt < 4; rt++)
    #pragma unroll
    for (int ci = 0; ci < 2; ci++) acc[rt][ci] = (f32x4)(0.f);
  #pragma unroll
  for (int kc = 0; kc < 4; kc++) {
    short8 af[4];
    #pragma unroll
    for (int rt = 0; rt < 4; rt++) {
      int row = rt*16 + (l & 15), g = kc*4 + (l >> 4);
      af[rt] = *(const short8*)&As[row*136 + g*8];
    }
    short8 bf[2];
    #pragma unroll
    for (int ci = 0; ci < 2; ci++) {
      int ct = (cb >> 4) + wv*2 + ci;
      bf[ci] = *(const short8*)&Wp[(((size_t)ct*4 + kc)*64 + l)*8];
    }
    #pragma unroll
    for (int rt = 0; rt < 4; rt++)
      #pragma unroll
      for (int ci = 0; ci < 2; ci++)
        acc[rt][ci] = __builtin_amdgcn_mfma_f32_16x16x32_bf16(af[rt], bf[ci], acc[rt][ci], 0, 0, 0);
  }
  #pragma unroll
  for (int ci = 0; ci < 2; ci++) {
    int cl = cb + wv*32 + ci*16 + (l & 15);
    float bias = b0[cl] + (b1 ? b1[cl] : 0.f);
    #pragma unroll
    for (int rt = 0; rt < 4; rt++)
      #pragma unroll
      for (int r = 0; r < 4; r++) {
        int row = r0 + rt*16 + (l >> 4)*4 + r;
        float v = acc[rt][ci][r] + bias;
        if (outmode == 0) ((float*)out)[(size_t)row*out_ld + cl] = v;
        else ((unsigned short*)out)[(size_t)row*out_ld + cl] = f2h(v);
      }
  }
}

// ---------------- single-layer LSTM scan, fdot2 f16, 512 thr ---------------
// One block per batch element. Thread tid holds whh row tid as 64 packed-f16
// uints (VGPR-resident: 8-wave blocks get a 128-VGPR budget; need ~100).
// vs r10's 256-thr/2-rows: 2 waves/SIMD (was 1) for LDS-latency hiding and
// half the per-thread matvec issue. pre is f16 with biases folded (k_mm
// outmode=1); 1 elem/thread loaded at step-top, consumed after the matvec.
__global__ __launch_bounds__(512, 1) void k_lscan(
    const unsigned short* __restrict__ pre,   // f16 [B][T][512] (tstr=512) or [B][512] (tstr=0)
    const float* __restrict__ whh,
    const float* __restrict__ h0i, const float* __restrict__ c0i,
    int T, int tstr,
    unsigned short* __restrict__ ys,          // bf16 [B][T][128]
    float* __restrict__ hT, float* __restrict__ cT,
    unsigned short* __restrict__ hTb)         // bf16 [B][128]
{
  const int b = blockIdx.x, tid = threadIdx.x;
  unsigned int w[64];
  {
    const float* p0 = whh + (size_t)tid*128;
    #pragma unroll
    for (int k = 0; k < 64; k++) w[k] = pkh(p0[2*k], p0[2*k+1]);
  }
  __shared__ __align__(16) unsigned short hs[128];
  __shared__ float fg[512];
  float c = 0.f;
  if (tid < 128) {
    float h = h0i ? h0i[(size_t)b*128 + tid] : 0.f;
    c = c0i ? c0i[(size_t)b*128 + tid] : 0.f;
    hs[tid] = f2h(h);
  }
  __syncthreads();
  const unsigned short* preb = pre + (size_t)b * (tstr ? (size_t)T*tstr : 512);
  for (int t = 0; t < T; t++) {
    unsigned short p = preb[(size_t)t*tstr + tid];
    float a0 = 0.f, a1 = 0.f, a2 = 0.f, a3 = 0.f;
    #pragma unroll
    for (int k4 = 0; k4 < 16; k4++) {
      uint4 hh = *(const uint4*)&hs[k4*8];
      a0 = fd2(w[4*k4+0], hh.x, a0);
      a1 = fd2(w[4*k4+1], hh.y, a1);
      a2 = fd2(w[4*k4+2], hh.z, a2);
      a3 = fd2(w[4*k4+3], hh.w, a3);
    }
    fg[tid] = h2f(p) + (a0+a1) + (a2+a3);
    __syncthreads();
    if (tid < 128) {
      float iv = sigm (fg[tid]);
      float fv = sigm (fg[128 + tid]);
      float gv = tanhx(fg[256 + tid]);
      float ov = sigm (fg[384 + tid]);
      c = fv*c + iv*gv;
      float h = ov * tanhx(c);
      hs[tid] = f2h(h);
      ys[((size_t)b*T + t)*128 + tid] = f2bu(h);
      if (t == T-1) {
        hT[(size_t)b*128 + tid] = h;
        cT[(size_t)b*128 + tid] = c;
        hTb[(size_t)b*128 + tid] = f2bu(h);
      }
    }
    __syncthreads();
  }
}

// ---------------- cross attention: one block per (batch, head) -------------
__global__ __launch_bounds__(256) void k_attn(
    const float* __restrict__ Q, const float* __restrict__ K, const float* __restrict__ V,
    unsigned short* __restrict__ o)
{
  const int b = blockIdx.x, h = blockIdx.y, tid = threadIdx.x;
  __shared__ float Ks[168][33];
  __shared__ float Vs[168][32];
  __shared__ float Qs[24][32];
  __shared__ float Sc[24][169];
  __shared__ float red[24][8];
  __shared__ float rowm[24], rows[24];
  for (int e = tid; e < 168*32; e += 256) {
    int t = e >> 5, d = e & 31;
    Ks[t][d] = K[((size_t)b*168 + t)*128 + h*32 + d];
    Vs[t][d] = V[((size_t)b*168 + t)*128 + h*32 + d];
  }
  for (int e = tid; e < 24*32; e += 256) {
    int q = e >> 5, d = e & 31;
    Qs[q][d] = Q[((size_t)b*24 + q)*128 + h*32 + d];
  }
  __syncthreads();
  for (int e = tid; e < 24*168; e += 256) {
    int q = e / 168, t = e - q*168;
    float s = 0.f;
    #pragma unroll
    for (int d = 0; d < 32; d++) s += Qs[q][d]*Ks[t][d];
    Sc[q][t] = s * 0.17677669529663687f;
  }
  __syncthreads();
  int q = tid >> 3, l8 = tid & 7;
  if (q < 24) {
    float m = -1e30f;
    for (int t = l8; t < 168; t += 8) m = fmaxf(m, Sc[q][t]);
    red[q][l8] = m;
  }
  __syncthreads();
  if (q < 24 && l8 == 0) {
    float m = red[q][0];
    for (int p = 1; p < 8; p++) m = fmaxf(m, red[q][p]);
    rowm[q] = m;
  }
  __syncthreads();
  if (q < 24) {
    float s = 0.f;
    for (int t = l8; t < 168; t += 8) {
      float e2 = __expf(Sc[q][t] - rowm[q]);
      Sc[q][t] = e2; s += e2;
    }
    red[q][l8] = s;
  }
  __syncthreads();
  if (q < 24 && l8 == 0) {
    float s = 0.f;
    for (int p = 0; p < 8; p++) s += red[q][p];
    rows[q] = 1.f/s;
  }
  __syncthreads();
  for (int e = tid; e < 24*32; e += 256) {
    int qq = e >> 5, d = e & 31;
    float acc = 0.f;
    for (int t = 0; t < 168; t++) acc += Sc[qq][t]*Vs[t][d];
    o[((size_t)b*24 + qq)*128 + h*32 + d] = f2bu(acc * rows[qq]);
  }
}

// ---------------- post-attention GRN (MFMA, identity skip) -----------------
// 64 tokens/block, 96 blocks. Phase 1: x@fc1 (128 cols) -> elu -> A2s bf16.
// Phase 2: h1@[fc2|gate] (256 cols, paired). v = x + h*sigm(g); LN -> fp32.
__global__ __launch_bounds__(256) void k_pa_mfma(
    const float* __restrict__ xin, const unsigned short* __restrict__ pk,
    const float* __restrict__ fc1_b, const float* __restrict__ fc2_b,
    const float* __restrict__ gate_b, const float* __restrict__ ln_g,
    const float* __restrict__ ln_b, float* __restrict__ out)
{
  const int n0 = blockIdx.x * 64;
  const int tid = threadIdx.x;
  const int wv = tid >> 6, l = tid & 63;
  __shared__ __align__(16) unsigned short As[64*136];
  __shared__ __align__(16) unsigned short A2s[64*136];
  __shared__ float xs[64*129];
  __shared__ float red[64][4][2];
  __shared__ float mr[64][2];
  for (int i2 = 0; i2 < 8; i2++) {
    int t4 = i2*256 + tid;
    int r = t4 >> 5, cc = (t4 & 31) << 2;
    float4 v = *(const float4*)(xin + (size_t)(n0 + r)*128 + cc);
    xs[r*129 + cc] = v.x; xs[r*129 + cc+1] = v.y;
    xs[r*129 + cc+2] = v.z; xs[r*129 + cc+3] = v.w;
    As[r*136 + cc] = f2bu(v.x); As[r*136 + cc+1] = f2bu(v.y);
    As[r*136 + cc+2] = f2bu(v.z); As[r*136 + cc+3] = f2bu(v.w);
  }
  __syncthreads();
  const unsigned short* W1 = pk + PK_PAF1;
  f32x4 acc1[4][2];
  #pragma unroll
  for (int rt = 0; rt < 4; rt++)
    #pragma unroll
    for (int ci = 0; ci < 2; ci++) acc1[rt][ci] = (f32x4)(0.f);
  #pragma unroll
  for (int kc = 0; kc < 4; kc++) {
    short8 af[4];
    #pragma unroll
    for (int rt = 0; rt < 4; rt++) {
      int row = rt*16 + (l & 15), g = kc*4 + (l >> 4);
      af[rt] = *(const short8*)&As[row*136 + g*8];
    }
    short8 bf[2];
    #pragma unroll
    for (int ci = 0; ci < 2; ci++) {
      int ct = wv*2 + ci;
      bf[ci] = *(const short8*)&W1[(((size_t)ct*4 + kc)*64 + l)*8];
    }
    #pragma unroll
    for (int rt = 0; rt < 4; rt++)
      #pragma unroll
      for (int ci = 0; ci < 2; ci++)
        acc1[rt][ci] = __builtin_amdgcn_mfma_f32_16x16x32_bf16(af[rt], bf[ci], acc1[rt][ci], 0, 0, 0);
  }
  __syncthreads();
  #pragma unroll
  for (int ci = 0; ci < 2; ci++) {
    int ch = wv*32 + ci*16 + (l & 15);
    float fb = fc1_b[ch];
    #pragma unroll
    for (int rt = 0; rt < 4; rt++)
      #pragma unroll
      for (int r = 0; r < 4; r++) {
        int row = rt*16 + (l >> 4)*4 + r;
        A2s[row*136 + ch] = f2bu(eluf(acc1[rt][ci][r] + fb));
      }
  }
  __syncthreads();
  const unsigned short* W2 = pk + PK_PAF2G;
  f32x4 acc2[4][4];
  #pragma unroll
  for (int rt = 0; rt < 4; rt++)
    #pragma unroll
    for (int ci = 0; ci < 4; ci++) acc2[rt][ci] = (f32x4)(0.f);
  #pragma unroll
  for (int kc = 0; kc < 4; kc++) {
    short8 af[4];
    #pragma unroll
    for (int rt = 0; rt < 4; rt++) {
      int row = rt*16 + (l & 15), g = kc*4 + (l >> 4);
      af[rt] = *(const short8*)&A2s[row*136 + g*8];
    }
    short8 bf[4];
    #pragma unroll
    for (int ci = 0; ci < 4; ci++) {
      int ct = (ci < 2) ? (wv*2 + ci) : (8 + wv*2 + (ci-2));
      bf[ci] = *(const short8*)&W2[(((size_t)ct*4 + kc)*64 + l)*8];
    }
    #pragma unroll
    for (int rt = 0; rt < 4; rt++)
      #pragma unroll
      for (int ci = 0; ci < 4; ci++)
        acc2[rt][ci] = __builtin_amdgcn_mfma_f32_16x16x32_bf16(af[rt], bf[ci], acc2[rt][ci], 0, 0, 0);
  }
  __syncthreads();
  #pragma unroll
  for (int ci = 0; ci < 2; ci++) {
    int ch = wv*32 + ci*16 + (l & 15);
    float f2 = fc2_b[ch], gb = gate_b[ch];
    #pragma unroll
    for (int rt = 0; rt < 4; rt++)
      #pragma unroll
      for (int r = 0; r < 4; r++) {
        int row = rt*16 + (l >> 4)*4 + r;
        float hv = acc2[rt][ci][r] + f2;
        float gv = sigm(acc2[rt][ci+2][r] + gb);
        xs[row*129 + ch] = xs[row*129 + ch] + hv*gv;
      }
  }
  __syncthreads();
  { int tk = tid >> 2, q = tid & 3;
    float s1 = 0.f, s2 = 0.f;
    #pragma unroll
    for (int i = 0; i < 32; i++) { float z = xs[tk*129 + q*32 + i]; s1 += z; s2 += z*z; }
    red[tk][q][0] = s1; red[tk][q][1] = s2;
  }
  __syncthreads();
  if ((tid & 3) == 0) {
    int tk = tid >> 2;
    float a = 0.f, b2 = 0.f;
    for (int p = 0; p < 4; p++) { a += red[tk][p][0]; b2 += red[tk][p][1]; }
    float mean = a * 0.0078125f;
    float var = b2 * 0.0078125f - mean*mean;
    mr[tk][0] = mean; mr[tk][1] = rsqrtf(fmaxf(var, 0.f) + 1e-5f);
  }
  __syncthreads();
  { int i = tid & 127;
    float lg = ln_g[i], lb = ln_b[i];
    for (int it = 0; it < 32; it++) {
      int tk = (tid >> 7) + it*2;
      out[(size_t)(n0+tk)*128 + i] = (xs[tk*129 + i] - mr[tk][0]) * mr[tk][1] * lg + lb;
    }
  }
}

// ---------------- final projection 128 -> 6 --------------------------------
__global__ __launch_bounds__(256) void k_final(
    const float* __restrict__ a, const float* __restrict__ fo_w,
    const float* __restrict__ fo_b, float* __restrict__ out)
{
  int idx = blockIdx.x*256 + threadIdx.x;
  if (idx >= NDTOK*6) return;
  int n = idx / 6, j = idx - n*6;
  const float* ar = a + (size_t)n*128;
  const float* w = fo_w + j*128;
  float s = fo_b[j];
  #pragma unroll 4
  for (int d = 0; d < 128; d++) s += ar[d]*w[d];
  out[idx] = s;
}

extern "C" void kernel_launch(void* const* d_in, const int* in_sizes, int n_in,
                              void* d_out, int out_size, void* d_ws, size_t ws_size,
                              hipStream_t stream) {
  (void)in_sizes; (void)n_in; (void)out_size; (void)ws_size;
  const float* x      = (const float*)d_in[0];
  const float* vfc1w  = (const float*)d_in[1];
  const float* vfc1b  = (const float*)d_in[2];
  const float* vfc2w  = (const float*)d_in[3];
  const float* vfc2b  = (const float*)d_in[4];
  const float* vgw    = (const float*)d_in[5];
  const float* vgb    = (const float*)d_in[6];
  const float* vskw   = (const float*)d_in[7];
  const float* vskb   = (const float*)d_in[8];
  const float* vlng   = (const float*)d_in[9];
  const float* vlnb   = (const float*)d_in[10];
  const float* gfc1w  = (const float*)d_in[11];
  const float* gfc1b  = (const float*)d_in[12];
  const float* gfc2w  = (const float*)d_in[13];
  const float* gfc2b  = (const float*)d_in[14];
  const float* ggw    = (const float*)d_in[15];
  const float* ggb    = (const float*)d_in[16];
  const float* gskw   = (const float*)d_in[17];
  const float* gskb   = (const float*)d_in[18];
  const float* glng   = (const float*)d_in[19];
  const float* glnb   = (const float*)d_in[20];
  const float* encwih = (const float*)d_in[21];
  const float* encwhh = (const float*)d_in[22];
  const float* encbih = (const float*)d_in[23];
  const float* encbhh = (const float*)d_in[24];
  const float* decwih = (const float*)d_in[25];
  const float* decwhh = (const float*)d_in[26];
  const float* decbih = (const float*)d_in[27];
  const float* decbhh = (const float*)d_in[28];
  const float* ainw   = (const float*)d_in[29];
  const float* ainb   = (const float*)d_in[30];
  const float* aoutw  = (const float*)d_in[31];
  const float* aoutb  = (const float*)d_in[32];
  const float* pfc1w  = (const float*)d_in[33];
  const float* pfc1b  = (const float*)d_in[34];
  const float* pfc2w  = (const float*)d_in[35];
  const float* pfc2b  = (const float*)d_in[36];
  const float* pgw    = (const float*)d_in[37];
  const float* pgb    = (const float*)d_in[38];
  const float* plng   = (const float*)d_in[39];
  const float* plnb   = (const float*)d_in[40];
  const float* fow    = (const float*)d_in[41];
  const float* fob    = (const float*)d_in[42];

  float* ws = (float*)d_ws;
  // ---- workspace (float offsets). Sizes: bf16/f16 [43008,128]=2,752,512 fl;
  // f16 [43008,512]=11,010,048 fl; proc2=24,772,608 fl; pk=999,424 us=499,712 fl.
  unsigned short* pk = (unsigned short*)ws;               // [0, 499,712)
  unsigned short* proc2 = (unsigned short*)(ws + 530000); // [530,000, 25,302,608)
  unsigned short* pre = (unsigned short*)(ws + 530000);   // f16 [43008][512] alias (proc2 dead) -> 11,540,048
  float* Kb   = ws + 530000;                              // f32 [43008,128] (pre dead) -> 6,035,024
  float* Vb   = ws + 6100000;                             // -> 11,605,024
  unsigned short* pre2 = (unsigned short*)(ws + 11700000);// f16 [6144,512] -> 13,272,864
  float* Qb   = ws + 13300000;                            // -> 14,086,432
  unsigned short* attb = (unsigned short*)(ws + 14100000);// -> 14,296,608
  float* ato  = ws + 14300000;                            // -> 15,086,432
  float* pao  = ws + 15100000;                            // -> 15,886,432
  unsigned short* pd0 = (unsigned short*)(ws + 15900000); // f16 [256,512] -> 15,965,536
  unsigned short* selb  = (unsigned short*)(ws + 25350000); // bf16 [43008,128] -> 28,102,512
  unsigned short* encob = (unsigned short*)(ws + 28150000); // bf16 [43008,128] -> 30,902,512
  unsigned short* ys0b  = (unsigned short*)(ws + 30950000); // bf16 [43008,128] -> 33,702,512
  unsigned short* dys0b = (unsigned short*)(ws + 33750000); // bf16 [6144,128] -> 33,946,608
  unsigned short* dout2b = (unsigned short*)(ws + 33950000);// bf16 [6144,128] -> 34,146,608
  float* hT0  = ws + 34150000;  float* cT0 = ws + 34190000;
  float* hT1  = ws + 34230000;  float* cT1 = ws + 34270000;
  unsigned short* hT1b = (unsigned short*)(ws + 34310000);  // bf16 [256,128]
  float* dscr = ws + 34350000;  // dummy hT/cT/hTb for scans that don't need them

  // 1. pack bf16 MFMA fragments
  k_pack<<<dim3(128, 9), dim3(256), 0, stream>>>(vfc2w, vgw, pk + PK_VSN, 128, 256, 128, 16384, 16384, 32768);
  k_pack<<<dim3(1152), dim3(256), 0, stream>>>(gfc1w, gskw, pk + PK_GC1, 1152, 256, 128, 0, 0, 0);
  k_pack<<<dim3(128), dim3(256), 0, stream>>>(gfc2w, ggw, pk + PK_GC2, 128, 256, 128, 0, 0, 0);
  k_pack<<<dim3(256), dim3(256), 0, stream>>>(encwih, encwih, pk + PK_ENC0, 128, 512, 512, 0, 0, 0);
  k_pack<<<dim3(256), dim3(256), 0, stream>>>(encwih + 65536, encwih, pk + PK_ENC1, 128, 512, 512, 0, 0, 0);
  k_pack<<<dim3(256), dim3(256), 0, stream>>>(decwih, decwih, pk + PK_DEC0, 128, 512, 512, 0, 0, 0);
  k_pack<<<dim3(256), dim3(256), 0, stream>>>(decwih + 65536, decwih, pk + PK_DEC1, 128, 512, 512, 0, 0, 0);
  k_pack<<<dim3(192), dim3(256), 0, stream>>>(ainw, ainw, pk + PK_AIN, 128, 384, 384, 0, 0, 0);
  k_pack<<<dim3(64), dim3(256), 0, stream>>>(aoutw, aoutw, pk + PK_AOUT, 128, 128, 128, 0, 0, 0);
  k_pack<<<dim3(64), dim3(256), 0, stream>>>(pfc1w, pfc1w, pk + PK_PAF1, 128, 128, 128, 0, 0, 0);
  k_pack<<<dim3(128), dim3(256), 0, stream>>>(pfc2w, pgw, pk + PK_PAF2G, 128, 256, 128, 0, 0, 0);
  // 2. VSN per-feature GRNs (MFMA)
  k_vsn_mfma<<<dim3(672, 9), dim3(256), 0, stream>>>(x, vfc1w, vfc1b, pk,
      vfc2b, vgb, vskw, vskb, vlng, vlnb, proc2);
  // 3. grand-selection GRN (MFMA, fused)
  k_gc_mfma<<<dim3(672), dim3(256), 0, stream>>>(proc2, pk, gfc1b, gfc2b, ggb,
      gskb, glng, glnb, selb);
  // 4. encoder layer 0: input projection (f16, biases folded) + scan
  k_mm<<<dim3(672, 4), dim3(256), 0, stream>>>(selb, pk + PK_ENC0, encbih, encbhh, pre, 512, 1);
  k_lscan<<<dim3(256), dim3(512), 0, stream>>>(pre, encwhh, nullptr, nullptr,
      TSE, 512, ys0b, hT0, cT0, (unsigned short*)dscr);
  // 5. encoder layer 1
  k_mm<<<dim3(672, 4), dim3(256), 0, stream>>>(ys0b, pk + PK_ENC1, encbih + 512, encbhh + 512, pre, 512, 1);
  k_lscan<<<dim3(256), dim3(512), 0, stream>>>(pre, encwhh + 65536, nullptr, nullptr,
      TSE, 512, encob, hT1, cT1, hT1b);
  // 6. decoder layer 0 (constant input hT1)
  k_mm<<<dim3(4, 4), dim3(256), 0, stream>>>(hT1b, pk + PK_DEC0, decbih, decbhh, pd0, 512, 1);
  k_lscan<<<dim3(256), dim3(512), 0, stream>>>(pd0, decwhh, hT0, cT0,
      TSD, 0, dys0b, dscr + 40000, dscr + 80000, (unsigned short*)dscr);
  // 7. decoder layer 1
  k_mm<<<dim3(96, 4), dim3(256), 0, stream>>>(dys0b, pk + PK_DEC1, decbih + 512, decbhh + 512, pre2, 512, 1);
  k_lscan<<<dim3(256), dim3(512), 0, stream>>>(pre2, decwhh + 65536, hT1, cT1,
      TSD, 512, dout2b, dscr + 120000, dscr + 160000, (unsigned short*)dscr);
  // 8. attention projections
  k_mm<<<dim3(96, 1), dim3(256), 0, stream>>>(dout2b, pk + PK_AIN, ainb, nullptr, Qb, 128, 0);
  k_mm<<<dim3(672, 1), dim3(256), 0, stream>>>(encob, pk + PK_AIN + 16384, ainb + 128, nullptr, Kb, 128, 0);
  k_mm<<<dim3(672, 1), dim3(256), 0, stream>>>(encob, pk + PK_AIN + 32768, ainb + 256, nullptr, Vb, 128, 0);
  // 9. attention core
  k_attn<<<dim3(256, 4), dim3(256), 0, stream>>>(Qb, Kb, Vb, attb);
  // 10. attention output projection
  k_mm<<<dim3(96, 1), dim3(256), 0, stream>>>(attb, pk + PK_AOUT, aoutb, nullptr, ato, 128, 0);
  // 11. post-attention GRN (MFMA)
  k_pa_mfma<<<dim3(96), dim3(256), 0, stream>>>(ato, pk, pfc1b, pfc2b, pgb,
      plng, plnb, pao);
  // 12. final projection
  k_final<<<dim3(144), dim3(256), 0, stream>>>(pao, fow, fob, (float*)d_out);
}